// Round 7
// baseline (599.903 us; speedup 1.0000x reference)
//
#include <hip/hip_runtime.h>
#include <math.h>

#define SS 512
#define BB 16
#define DD 768
#define HH 12
#define HDIM 64
#define EE 8
#define HID 3072
#define TT 8192   // SS*BB tokens
#define EPSV 1e-5f
#define KVSTR 1536
#define ASTR 72   // attention LDS row stride in shorts (144 B, 16B-aligned)
#define NBANK 64  // routing histogram banks

typedef __attribute__((ext_vector_type(8))) short s16x8;
typedef __attribute__((ext_vector_type(4))) short s16x4;
typedef __attribute__((ext_vector_type(4))) float f32x4;

__device__ inline short f2bf(float f) {
  unsigned u = __builtin_bit_cast(unsigned, f);
  unsigned r = (u + 0x7fffu + ((u >> 16) & 1u)) >> 16;
  return (short)r;
}

// tanh-form GELU (max abs err ~3e-4, invisible under bf16 pipeline noise)
__device__ inline float gelu_f(float x) {
  float y = 0.7978845608028654f * (x + 0.044715f * x * x * x);
  float e = __expf(2.f * y);
  float t = 1.f - 2.f / (e + 1.f);
  return 0.5f * x * (1.f + t);
}

// async global->LDS DMA, 16B per lane; LDS dest = wave-uniform base + lane*16
__device__ inline void gl2lds16(const void* g, void* l) {
  __builtin_amdgcn_global_load_lds(
      (const __attribute__((address_space(1))) unsigned int*)g,
      (__attribute__((address_space(3))) unsigned int*)l, 16, 0, 0);
}

// ---------------- 4x DxD transpose + convert in one launch ----------------
__global__ __launch_bounds__(256) void transpose4_bf16(const float* __restrict__ w0,
    const float* __restrict__ w1p, const float* __restrict__ w2p,
    const float* __restrict__ w3p, short* __restrict__ dst) {
  const int z = blockIdx.z;
  const float* W = (z == 0) ? w0 : (z == 1) ? w1p : (z == 2) ? w2p : w3p;
  short* Wt = dst + (size_t)z * DD * DD;
  int k0 = blockIdx.x * 64, n0 = blockIdx.y * 64;
  __shared__ float t[64][65];
  for (int i = threadIdx.x; i < 1024; i += 256) {
    int r = i >> 4, c4 = (i & 15) << 2;
    const float4 v = *(const float4*)(W + (size_t)(k0 + r) * DD + n0 + c4);
    t[r][c4] = v.x; t[r][c4 + 1] = v.y; t[r][c4 + 2] = v.z; t[r][c4 + 3] = v.w;
  }
  __syncthreads();
  for (int i = threadIdx.x; i < 1024; i += 256) {
    int r = i >> 4, c4 = (i & 15) << 2;
    s16x4 sv;
    sv.x = f2bf(t[c4][r]);     sv.y = f2bf(t[c4 + 1][r]);
    sv.z = f2bf(t[c4 + 2][r]); sv.w = f2bf(t[c4 + 3][r]);
    *(s16x4*)(Wt + (size_t)(n0 + r) * DD + k0 + c4) = sv;
  }
}

// ---------------- transpose + convert: W[K,N] fp32 -> Wt[N,K] bf16 ----------------
__global__ __launch_bounds__(256) void transpose_bf16(const float* __restrict__ W,
    short* __restrict__ Wt, int K, int N) {
  const float* Wz = W + (size_t)blockIdx.z * K * N;
  short* Wtz = Wt + (size_t)blockIdx.z * K * N;
  int k0 = blockIdx.x * 64, n0 = blockIdx.y * 64;
  __shared__ float t[64][65];
  for (int i = threadIdx.x; i < 1024; i += 256) {
    int r = i >> 4, c4 = (i & 15) << 2;
    const float4 v = *(const float4*)(Wz + (size_t)(k0 + r) * N + n0 + c4);
    t[r][c4] = v.x; t[r][c4 + 1] = v.y; t[r][c4 + 2] = v.z; t[r][c4 + 3] = v.w;
  }
  __syncthreads();
  for (int i = threadIdx.x; i < 1024; i += 256) {
    int r = i >> 4, c4 = (i & 15) << 2;
    s16x4 sv;
    sv.x = f2bf(t[c4][r]);     sv.y = f2bf(t[c4 + 1][r]);
    sv.z = f2bf(t[c4 + 2][r]); sv.w = f2bf(t[c4 + 3][r]);
    *(s16x4*)(Wtz + (size_t)(n0 + r) * K + k0 + c4) = sv;
  }
}

// ---------------- gating weight transpose: wg[D,E] fp32 -> wgT[E,D] fp32 ----------
__global__ __launch_bounds__(256) void gate_transpose(const float* __restrict__ wg,
    float* __restrict__ wgT) {
  for (int i = threadIdx.x + blockIdx.x * 256; i < EE * DD; i += 256 * 8) {
    int e = i / DD, d = i - e * DD;
    wgT[i] = wg[d * EE + e];
  }
}

// ---------------- fused x->bf16 convert + LayerNorm1 (wave-per-token) ----------------
__global__ __launch_bounds__(256) void fused_cvt_ln1(const float* __restrict__ x,
    const float* __restrict__ w, const float* __restrict__ b,
    short* __restrict__ xbf, short* __restrict__ ln1bf) {
  const int tok = blockIdx.x * 4 + (threadIdx.x >> 6);
  const int lane = threadIdx.x & 63;
  const float* row = x + (size_t)tok * DD;
  const float4 v0 = *(const float4*)(row + lane * 4);
  const float4 v1 = *(const float4*)(row + 256 + lane * 4);
  const float4 v2 = *(const float4*)(row + 512 + lane * 4);
  float s = v0.x + v0.y + v0.z + v0.w + v1.x + v1.y + v1.z + v1.w
          + v2.x + v2.y + v2.z + v2.w;
  float ss = v0.x * v0.x + v0.y * v0.y + v0.z * v0.z + v0.w * v0.w
           + v1.x * v1.x + v1.y * v1.y + v1.z * v1.z + v1.w * v1.w
           + v2.x * v2.x + v2.y * v2.y + v2.z * v2.z + v2.w * v2.w;
#pragma unroll
  for (int o = 1; o < 64; o <<= 1) { s += __shfl_xor(s, o); ss += __shfl_xor(ss, o); }
  const float mean = s * (1.f / DD);
  const float inv = rsqrtf(ss * (1.f / DD) - mean * mean + EPSV);
  short* xrow = xbf + (size_t)tok * DD;
  short* lrow = ln1bf + (size_t)tok * DD;
#define LN1_CHUNK(v, off) { \
  const float4 wv = *(const float4*)(w + (off) + lane * 4); \
  const float4 bv = *(const float4*)(b + (off) + lane * 4); \
  s16x4 xa, la; \
  xa.x = f2bf(v.x); xa.y = f2bf(v.y); xa.z = f2bf(v.z); xa.w = f2bf(v.w); \
  la.x = f2bf((v.x - mean) * inv * wv.x + bv.x); \
  la.y = f2bf((v.y - mean) * inv * wv.y + bv.y); \
  la.z = f2bf((v.z - mean) * inv * wv.z + bv.z); \
  la.w = f2bf((v.w - mean) * inv * wv.w + bv.w); \
  *(s16x4*)(xrow + (off) + lane * 4) = xa; \
  *(s16x4*)(lrow + (off) + lane * 4) = la; }
  LN1_CHUNK(v0, 0)
  LN1_CHUNK(v1, 256)
  LN1_CHUNK(v2, 512)
#undef LN1_CHUNK
}

// ---------------- fused LayerNorm2 + MoE routing (wave-per-token) ----------------
__global__ __launch_bounds__(256) void fused_ln2_route(const float* __restrict__ x1,
    const float* __restrict__ w, const float* __restrict__ b,
    const float* __restrict__ wgT, const float* __restrict__ bg,
    short* __restrict__ tlnbf, int* __restrict__ idx, float* __restrict__ gate,
    int* __restrict__ cnt2) {
  const int tok = blockIdx.x * 4 + (threadIdx.x >> 6);
  const int lane = threadIdx.x & 63;
  const float* row = x1 + (size_t)tok * DD;
  const float4 v0 = *(const float4*)(row + lane * 4);
  const float4 v1 = *(const float4*)(row + 256 + lane * 4);
  const float4 v2 = *(const float4*)(row + 512 + lane * 4);
  float s = v0.x + v0.y + v0.z + v0.w + v1.x + v1.y + v1.z + v1.w
          + v2.x + v2.y + v2.z + v2.w;
  float ss = v0.x * v0.x + v0.y * v0.y + v0.z * v0.z + v0.w * v0.w
           + v1.x * v1.x + v1.y * v1.y + v1.z * v1.z + v1.w * v1.w
           + v2.x * v2.x + v2.y * v2.y + v2.z * v2.z + v2.w * v2.w;
#pragma unroll
  for (int o = 1; o < 64; o <<= 1) { s += __shfl_xor(s, o); ss += __shfl_xor(ss, o); }
  const float mean = s * (1.f / DD);
  const float inv = rsqrtf(ss * (1.f / DD) - mean * mean + EPSV);
  short* srow = tlnbf + (size_t)tok * DD;
  float acc[EE];
#pragma unroll
  for (int e = 0; e < EE; ++e) acc[e] = 0.f;
#define LN2_CHUNK(v, off) { \
  const float4 wv = *(const float4*)(w + (off) + lane * 4); \
  const float4 bv = *(const float4*)(b + (off) + lane * 4); \
  float4 n; \
  n.x = (v.x - mean) * inv * wv.x + bv.x; \
  n.y = (v.y - mean) * inv * wv.y + bv.y; \
  n.z = (v.z - mean) * inv * wv.z + bv.z; \
  n.w = (v.w - mean) * inv * wv.w + bv.w; \
  s16x4 sv; sv.x = f2bf(n.x); sv.y = f2bf(n.y); sv.z = f2bf(n.z); sv.w = f2bf(n.w); \
  *(s16x4*)(srow + (off) + lane * 4) = sv; \
  const int i0 = (off) + lane * 4; \
  _Pragma("unroll") \
  for (int e = 0; e < EE; ++e) { \
    const float4 g = *(const float4*)(wgT + (size_t)e * DD + i0); \
    acc[e] += n.x * g.x + n.y * g.y + n.z * g.z + n.w * g.w; } }
  LN2_CHUNK(v0, 0)
  LN2_CHUNK(v1, 256)
  LN2_CHUNK(v2, 512)
#undef LN2_CHUNK
#pragma unroll
  for (int o = 1; o < 64; o <<= 1)
#pragma unroll
    for (int e = 0; e < EE; ++e) acc[e] += __shfl_xor(acc[e], o);
  if (lane == 0) {
#pragma unroll
    for (int e = 0; e < EE; ++e) acc[e] += bg[e];
    int best = 0; float bm = acc[0];
#pragma unroll
    for (int e = 1; e < EE; ++e) if (acc[e] > bm) { bm = acc[e]; best = e; }
    float sum = 0.f;
#pragma unroll
    for (int e = 0; e < EE; ++e) sum += __expf(acc[e] - bm);
    idx[tok] = best;
    gate[tok] = 1.0f / sum;
    atomicAdd(&cnt2[(blockIdx.x & (NBANK - 1)) * 16 + best], 1);
  }
}

// ---------------- prefix over banked histogram (1 wave) ----------------
__global__ void prefix2_kernel(const int* __restrict__ cnt2, int* __restrict__ cnt,
                               int* __restrict__ off, int* __restrict__ tb,
                               int* __restrict__ bankbase) {
  const int lane = threadIdx.x;   // 64 threads, 1 wave
  int c[EE], excl[EE], tot[EE];
#pragma unroll
  for (int e = 0; e < EE; ++e) c[e] = cnt2[lane * 16 + e];
#pragma unroll
  for (int e = 0; e < EE; ++e) {
    int x = c[e];
#pragma unroll
    for (int o = 1; o < 64; o <<= 1) {
      int y = __shfl_up(x, o);
      if (lane >= o) x += y;
    }
    excl[e] = x - c[e];
    tot[e] = __shfl(x, 63);
  }
  int oo = 0;
  int offl[EE];
#pragma unroll
  for (int e = 0; e < EE; ++e) { offl[e] = oo; oo += tot[e]; }
#pragma unroll
  for (int e = 0; e < EE; ++e)
    bankbase[lane * EE + e] = offl[e] + excl[e];
  if (lane == 0) {
    int o = 0, t = 0;
    for (int e = 0; e < EE; ++e) {
      off[e] = o; tb[e] = t; cnt[e] = tot[e];
      o += tot[e]; t += (tot[e] + 127) >> 7;
    }
    off[EE] = o; tb[EE] = t;
  }
}

// ---------------- scatter via banked cursors (low-contention atomics) ----------
__global__ __launch_bounds__(256) void scatter_kernel(const int* __restrict__ idx,
    const int* __restrict__ bankbase, int* __restrict__ cur2, int* __restrict__ perm) {
  int t = blockIdx.x * 256 + threadIdx.x;
  if (t < TT) {
    int e = idx[t];
    int bank = (t >> 2) & (NBANK - 1);
    int p = atomicAdd(&cur2[bank * 16 + e], 1);
    perm[bankbase[bank * EE + e] + p] = t;
  }
}

// ---------------- bf16 MFMA GEMM, DMA staging + XOR-swizzled LDS (BK=32) --------
template<int MODE, int OUTBF, int COLS>
__global__ __launch_bounds__(256) void mgemm(const short* __restrict__ A,
    const short* __restrict__ Wt, const float* __restrict__ bias,
    const float* __restrict__ bias2, const float* __restrict__ res,
    void* __restrict__ C, int N, int K) {
  const int bx = blockIdx.x;
  const int lid = bx >> 3;
  const int colt = lid >> 3, rband = lid & 7;
  const int bm = (((bx & 7) << 3) + rband) * 128;
  const int bn = colt * COLS;
  constexpr int NJ = COLS / 32;
  __shared__ short As[128 * 32];
  __shared__ short Bs[COLS * 32];
  const int tid = threadIdx.x;
  const int wave = tid >> 6, lane = tid & 63;
  const int wr = (wave >> 1) * 64, wc = (wave & 1) * (COLS / 2);
  const int l16 = lane & 15, quad = lane >> 4;
  const int kq = (((lane & 3) ^ ((lane >> 3) & 3)) << 3);
  const int sw = ((l16 >> 1) & 3);
  const short* Ab = A + (size_t)(bm + (wave << 5) + (lane >> 2)) * K + kq;
  const short* Bb = Wt + (size_t)(bn + wave * (COLS / 4) + (lane >> 2)) * K + kq;
  short* lA = &As[(wave << 5) * 32];
  short* lB = &Bs[wave * (COLS / 4) * 32];
  f32x4 acc[4][NJ] = {};
  for (int k0 = 0; k0 < K; k0 += 32) {
    gl2lds16(Ab + k0, lA);
    gl2lds16(Ab + (size_t)16 * K + k0, lA + 512);
    gl2lds16(Bb + k0, lB);
    if (COLS == 128) gl2lds16(Bb + (size_t)16 * K + k0, lB + 512);
    __syncthreads();
    s16x8 af[4], bfr[NJ];
#pragma unroll
    for (int i = 0; i < 4; ++i)
      af[i] = *(s16x8*)(&As[(wr + i * 16 + l16) * 32 + ((quad ^ sw) << 3)]);
#pragma unroll
    for (int j = 0; j < NJ; ++j)
      bfr[j] = *(s16x8*)(&Bs[(wc + j * 16 + l16) * 32 + ((quad ^ sw) << 3)]);
#pragma unroll
    for (int i = 0; i < 4; ++i)
#pragma unroll
      for (int j = 0; j < NJ; ++j)
        acc[i][j] = __builtin_amdgcn_mfma_f32_16x16x32_bf16(af[i], bfr[j], acc[i][j], 0, 0, 0);
    __syncthreads();
  }
#pragma unroll
  for (int i = 0; i < 4; ++i) {
#pragma unroll
    for (int r = 0; r < 4; ++r) {
      int row = bm + wr + i * 16 + quad * 4 + r;
#pragma unroll
      for (int j = 0; j < NJ; ++j) {
        int col = bn + wc + j * 16 + l16;
        float bv = (MODE == 2) ? (col >= DD ? bias2[col - DD] : bias[col]) : bias[col];
        float val = acc[i][j][r] + bv;
        if (MODE == 1) val += res[(size_t)row * N + col];
        if (OUTBF) ((short*)C)[(size_t)row * N + col] = f2bf(val);
        else       ((float*)C)[(size_t)row * N + col] = val;
      }
    }
  }
}

// ---------------- merged Q-proj + KV-proj (one launch, 1152 blocks) ----------------
__global__ __launch_bounds__(256) void qkv_mgemm(const short* __restrict__ ln1bf,
    const short* __restrict__ xbf, const short* __restrict__ wqT,
    const short* __restrict__ kvT, const float* __restrict__ bq,
    const float* __restrict__ bk, const float* __restrict__ bv,
    short* __restrict__ qbf, short* __restrict__ kvbf) {
  const int bx = blockIdx.x;
  const int lid = bx >> 3;
  const int colt = lid >> 3, rband = lid & 7;   // colt in [0,18)
  const int bm = (((bx & 7) << 3) + rband) * 128;
  const bool isQ = (colt < 6);
  const int bn = isQ ? colt * 128 : (colt - 6) * 128;
  const short* A  = isQ ? ln1bf : xbf;
  const short* Bt = isQ ? wqT : kvT;
  const float* bias = isQ ? bq : (bn < DD ? bk : bv);
  const int bofs = (!isQ && bn >= DD) ? DD : 0;
  short* out = isQ ? qbf : kvbf;
  const int OS = isQ ? DD : KVSTR;
  const int K = DD;
  __shared__ short As[128 * 32];
  __shared__ short Bs[128 * 32];
  const int tid = threadIdx.x;
  const int wave = tid >> 6, lane = tid & 63;
  const int wr = (wave >> 1) * 64, wc = (wave & 1) * 64;
  const int l16 = lane & 15, quad = lane >> 4;
  const int kq = (((lane & 3) ^ ((lane >> 3) & 3)) << 3);
  const int sw = ((l16 >> 1) & 3);
  const short* Ab = A + (size_t)(bm + (wave << 5) + (lane >> 2)) * K + kq;
  const short* Bb = Bt + (size_t)(bn + (wave << 5) + (lane >> 2)) * K + kq;
  short* lA = &As[(wave << 5) * 32];
  short* lB = &Bs[(wave << 5) * 32];
  f32x4 acc[4][4] = {};
  for (int k0 = 0; k0 < K; k0 += 32) {
    gl2lds16(Ab + k0, lA);
    gl2lds16(Ab + (size_t)16 * K + k0, lA + 512);
    gl2lds16(Bb + k0, lB);
    gl2lds16(Bb + (size_t)16 * K + k0, lB + 512);
    __syncthreads();
    s16x8 af[4], bfr[4];
#pragma unroll
    for (int i = 0; i < 4; ++i)
      af[i] = *(s16x8*)(&As[(wr + i * 16 + l16) * 32 + ((quad ^ sw) << 3)]);
#pragma unroll
    for (int j = 0; j < 4; ++j)
      bfr[j] = *(s16x8*)(&Bs[(wc + j * 16 + l16) * 32 + ((quad ^ sw) << 3)]);
#pragma unroll
    for (int i = 0; i < 4; ++i)
#pragma unroll
      for (int j = 0; j < 4; ++j)
        acc[i][j] = __builtin_amdgcn_mfma_f32_16x16x32_bf16(af[i], bfr[j], acc[i][j], 0, 0, 0);
    __syncthreads();
  }
#pragma unroll
  for (int i = 0; i < 4; ++i) {
#pragma unroll
    for (int r = 0; r < 4; ++r) {
      int row = bm + wr + i * 16 + quad * 4 + r;
#pragma unroll
      for (int j = 0; j < 4; ++j) {
        int col = bn + wc + j * 16 + l16;
        float val = acc[i][j][r] + bias[col - bofs];
        out[(size_t)row * OS + col] = f2bf(val);
      }
    }
  }
}

// ---------------- flash attention, bf16 MFMA, bf16 IO ----------------
__global__ __launch_bounds__(256) void attn_mfma(const short* __restrict__ q,
    const short* __restrict__ k, const short* __restrict__ v, short* __restrict__ o) {
  const int qt = blockIdx.x, bidx = blockIdx.y, hidx = blockIdx.z;
  const int tid = threadIdx.x;
  const int wave = tid >> 6, lane = tid & 63;
  const int l16 = lane & 15, quad = lane >> 4;
  const int s0 = qt * 64;
  __shared__ short Qs[64 * ASTR];
  __shared__ short Ks[64 * ASTR];
  __shared__ short Vs[64 * ASTR];   // transposed: Vs[d][key]
  __shared__ short Ps[64 * ASTR];
  for (int i = tid; i < 512; i += 256) {
    int r = i >> 3, c8 = i & 7;
    *(s16x8*)(&Qs[r * ASTR + c8 * 8]) =
        *(const s16x8*)(q + ((size_t)(s0 + r) * BB + bidx) * DD + hidx * HDIM + c8 * 8);
  }
  __syncthreads();
  s16x8 af0 = *(s16x8*)(&Qs[(wave * 16 + l16) * ASTR + quad * 8]);
  s16x8 af1 = *(s16x8*)(&Qs[(wave * 16 + l16) * ASTR + 32 + quad * 8]);
  f32x4 oacc[4] = {};
  float mr[4], lr[4];
#pragma unroll
  for (int r = 0; r < 4; ++r) { mr[r] = -1e30f; lr[r] = 0.f; }

  for (int t0 = 0; t0 < SS; t0 += 64) {
    __syncthreads();
    for (int i = tid; i < 512; i += 256) {
      int r = i >> 3, c8 = i & 7;
      *(s16x8*)(&Ks[r * ASTR + c8 * 8]) =
          *(const s16x8*)(k + ((size_t)(t0 + r) * BB + bidx) * KVSTR + hidx * HDIM + c8 * 8);
    }
    for (int i = tid; i < 1024; i += 256) {
      int r = i >> 4, c4 = i & 15;
      s16x4 vv = *(const s16x4*)(v + ((size_t)(t0 + r) * BB + bidx) * KVSTR + hidx * HDIM + c4 * 4);
      Vs[(c4 * 4 + 0) * ASTR + r] = vv.x;
      Vs[(c4 * 4 + 1) * ASTR + r] = vv.y;
      Vs[(c4 * 4 + 2) * ASTR + r] = vv.z;
      Vs[(c4 * 4 + 3) * ASTR + r] = vv.w;
    }
    __syncthreads();
    f32x4 sc[4];
    const f32x4 zero = {};
#pragma unroll
    for (int j = 0; j < 4; ++j) {
      s16x8 kf0 = *(s16x8*)(&Ks[(j * 16 + l16) * ASTR + quad * 8]);
      s16x8 kf1 = *(s16x8*)(&Ks[(j * 16 + l16) * ASTR + 32 + quad * 8]);
      sc[j] = __builtin_amdgcn_mfma_f32_16x16x32_bf16(af0, kf0, zero, 0, 0, 0);
      sc[j] = __builtin_amdgcn_mfma_f32_16x16x32_bf16(af1, kf1, sc[j], 0, 0, 0);
#pragma unroll
      for (int r = 0; r < 4; ++r) sc[j][r] *= 0.125f;
    }
    float tm[4], alpha[4], rs[4];
#pragma unroll
    for (int r = 0; r < 4; ++r) {
      tm[r] = mr[r];
#pragma unroll
      for (int j = 0; j < 4; ++j) tm[r] = fmaxf(tm[r], sc[j][r]);
    }
#pragma unroll
    for (int mask = 1; mask < 16; mask <<= 1)
#pragma unroll
      for (int r = 0; r < 4; ++r) tm[r] = fmaxf(tm[r], __shfl_xor(tm[r], mask));
#pragma unroll
    for (int r = 0; r < 4; ++r) { alpha[r] = __expf(mr[r] - tm[r]); mr[r] = tm[r]; rs[r] = 0.f; }
#pragma unroll
    for (int j = 0; j < 4; ++j)
#pragma unroll
      for (int r = 0; r < 4; ++r) {
        float p = __expf(sc[j][r] - tm[r]);
        sc[j][r] = p; rs[r] += p;
      }
#pragma unroll
    for (int mask = 1; mask < 16; mask <<= 1)
#pragma unroll
      for (int r = 0; r < 4; ++r) rs[r] += __shfl_xor(rs[r], mask);
#pragma unroll
    for (int r = 0; r < 4; ++r) lr[r] = lr[r] * alpha[r] + rs[r];
#pragma unroll
    for (int j = 0; j < 4; ++j)
#pragma unroll
      for (int r = 0; r < 4; ++r)
        Ps[(wave * 16 + quad * 4 + r) * ASTR + j * 16 + l16] = f2bf(sc[j][r]);
#pragma unroll
    for (int jd = 0; jd < 4; ++jd)
#pragma unroll
      for (int r = 0; r < 4; ++r) oacc[jd][r] *= alpha[r];
    __syncthreads();
    s16x8 pf0 = *(s16x8*)(&Ps[(wave * 16 + l16) * ASTR + quad * 8]);
    s16x8 pf1 = *(s16x8*)(&Ps[(wave * 16 + l16) * ASTR + 32 + quad * 8]);
#pragma unroll
    for (int jd = 0; jd < 4; ++jd) {
      s16x8 vf0 = *(s16x8*)(&Vs[(jd * 16 + l16) * ASTR + quad * 8]);
      s16x8 vf1 = *(s16x8*)(&Vs[(jd * 16 + l16) * ASTR + 32 + quad * 8]);
      oacc[jd] = __builtin_amdgcn_mfma_f32_16x16x32_bf16(pf0, vf0, oacc[jd], 0, 0, 0);
      oacc[jd] = __builtin_amdgcn_mfma_f32_16x16x32_bf16(pf1, vf1, oacc[jd], 0, 0, 0);
    }
  }
#pragma unroll
  for (int r = 0; r < 4; ++r) {
    int row = s0 + wave * 16 + quad * 4 + r;
    float invl = 1.f / lr[r];
#pragma unroll
    for (int jd = 0; jd < 4; ++jd) {
      int d = jd * 16 + l16;
      o[((size_t)row * BB + bidx) * DD + hidx * HDIM + d] = f2bf(oacc[jd][r] * invl);
    }
  }
}

// ---------------- expert GEMM 1 (BK=32, 2-phase dbuf): h = gelu(tln[perm]@w1[e]) --
// T3-minimum pipeline: STAGE(next,buf^1) -> vmcnt(4) -> raw barrier ->
// ds_read+MFMA(buf) -> lgkmcnt(0) -> raw barrier. Counted vmcnt keeps the
// next tile's 4 DMAs in flight across the compute phase (never drains to 0).
__global__ __launch_bounds__(256) void egemm1(const short* __restrict__ tlnbf,
    const short* __restrict__ w1t, const float* __restrict__ b1,
    const int* __restrict__ off, const int* __restrict__ tb, const int* __restrict__ cnt,
    const int* __restrict__ perm, short* __restrict__ hbuf) {
  const int bx = blockIdx.x;
  const int lid = bx >> 3;
  const int rband = lid % 9, colt = lid / 9;
  const int row = (bx & 7) * 9 + rband;
  if (row >= tb[EE]) return;
  int e = 0;
  while (e < EE - 1 && tb[e + 1] <= row) ++e;
  const int lt = row - tb[e];
  const int cnte = cnt[e];
  const int slot0 = off[e] + lt * 128;
  const int slast = off[e] + cnte - 1;
  const int bn = colt * 128;
  const int tid = threadIdx.x;
  const int wave = tid >> 6, lane = tid & 63;
  const int wr = (wave >> 1) * 64, wc = (wave & 1) * 64;
  const int l16 = lane & 15, quad = lane >> 4;
  const int kq = (((lane & 3) ^ ((lane >> 3) & 3)) << 3);
  const int sw = ((l16 >> 1) & 3);
  __shared__ short As[2][128 * 32];
  __shared__ short Bs[2][128 * 32];
  f32x4 acc[4][4] = {};
  const int sA = slot0 + (wave << 5) + (lane >> 2);
  const int tokA = perm[sA <= slast ? sA : slast];
  const int tokB = perm[(sA + 16) <= slast ? (sA + 16) : slast];
  const short* AbA = tlnbf + (size_t)tokA * DD + kq;
  const short* AbB = tlnbf + (size_t)tokB * DD + kq;
  const short* Bb = w1t + (size_t)e * DD * HID
                  + (size_t)(bn + (wave << 5) + (lane >> 2)) * DD + kq;
  const int lofs = (wave << 5) * 32;
#define STAGE_E1(p, k0) { \
  gl2lds16(AbA + (k0), &As[p][lofs]); \
  gl2lds16(AbB + (k0), &As[p][lofs + 512]); \
  gl2lds16(Bb + (k0), &Bs[p][lofs]); \
  gl2lds16(Bb + (size_t)16 * DD + (k0), &Bs[p][lofs + 512]); }
  STAGE_E1(0, 0)
  int p = 0;
  for (int t = 0; t < 24; ++t) {          // DD/32 = 24 K-steps
    const int kn = (t + 1 < 24 ? t + 1 : 23) * 32;
    STAGE_E1(p ^ 1, kn)
    asm volatile("s_waitcnt vmcnt(4)" ::: "memory");
    __builtin_amdgcn_s_barrier();
    s16x8 af[4], bfr[4];
#pragma unroll
    for (int i = 0; i < 4; ++i)
      af[i] = *(s16x8*)(&As[p][(wr + i * 16 + l16) * 32 + ((quad ^ sw) << 3)]);
#pragma unroll
    for (int j = 0; j < 4; ++j)
      bfr[j] = *(s16x8*)(&Bs[p][(wc + j * 16 + l16) * 32 + ((quad ^ sw) << 3)]);
#pragma unroll
    for (int i = 0; i < 4; ++i)
#pragma unroll
      for (int j = 0; j < 4; ++j)
        acc[i][j] = __builtin_amdgcn_mfma_f32_16x16x32_bf16(af[i], bfr[j], acc[i][j], 0, 0, 0);
    asm volatile("s_waitcnt lgkmcnt(0)" ::: "memory");
    __builtin_amdgcn_s_barrier();
    p ^= 1;
  }
#undef STAGE_E1
#pragma unroll
  for (int i = 0; i < 4; ++i) {
#pragma unroll
    for (int r = 0; r < 4; ++r) {
      int rl = wr + i * 16 + quad * 4 + r;
      if (lt * 128 + rl >= cnte) continue;
#pragma unroll
      for (int j = 0; j < 4; ++j) {
        int col = bn + wc + j * 16 + l16;
        float xv = acc[i][j][r] + b1[e * HID + col];
        hbuf[(size_t)(slot0 + rl) * HID + col] = f2bf(gelu_f(xv));
      }
    }
  }
}

// ---------------- expert GEMM 2 (BK=64, 128x64, 2-phase dbuf) --------------------
// out = x1 + gate*(h @ w2[e] + b2). Same counted-vmcnt pipeline, vmcnt(6).
__global__ __launch_bounds__(256) void egemm2(const short* __restrict__ hbuf,
    const short* __restrict__ w2t, const float* __restrict__ b2,
    const int* __restrict__ perm, const int* __restrict__ off,
    const int* __restrict__ tb, const int* __restrict__ cnt,
    const float* __restrict__ gate, const float* __restrict__ x1,
    float* __restrict__ out) {
  const int bx = blockIdx.x;
  const int lid = bx >> 3;
  const int colt = lid % 12, rband = lid / 12;
  const int row = (bx & 7) * 9 + rband;
  if (row >= tb[EE]) return;
  int e = 0;
  while (e < EE - 1 && tb[e + 1] <= row) ++e;
  const int lt = row - tb[e];
  const int cnte = cnt[e];
  const int slot0 = off[e] + lt * 128;
  const int bn = colt * 64;
  const int tid = threadIdx.x;
  const int wave = tid >> 6, lane = tid & 63;
  const int wr = (wave >> 1) * 64, wc = (wave & 1) * 32;
  const int l16 = lane & 15, quad = lane >> 4;
  const int rg = lane >> 3;
  const int kq8 = (((lane & 7) ^ rg) << 3);
  const int swz = l16 & 7;
  __shared__ short As[2][128 * 64];
  __shared__ short Bs[2][64 * 64];
  __shared__ int stok[128];
  if (tid < 128) stok[tid] = (lt * 128 + tid < cnte) ? perm[slot0 + tid] : -1;
  f32x4 acc[4][2] = {};
  const short* Ab = hbuf + (size_t)(slot0 + (wave << 5) + rg) * HID + kq8;
  const short* Bb = w2t + (size_t)e * HID * DD
                  + (size_t)(bn + wave * 16 + rg) * HID + kq8;
  const int lofsA = (wave << 5) * 64;
  const int lofsB = wave * 16 * 64;
#define STAGE_E2(p, k0) { \
  gl2lds16(Ab + (k0), &As[p][lofsA]); \
  gl2lds16(Ab + (size_t)8 * HID + (k0), &As[p][lofsA + 512]); \
  gl2lds16(Ab + (size_t)16 * HID + (k0), &As[p][lofsA + 1024]); \
  gl2lds16(Ab + (size_t)24 * HID + (k0), &As[p][lofsA + 1536]); \
  gl2lds16(Bb + (k0), &Bs[p][lofsB]); \
  gl2lds16(Bb + (size_t)8 * HID + (k0), &Bs[p][lofsB + 512]); }
  STAGE_E2(0, 0)
  int p = 0;
  for (int t = 0; t < 48; ++t) {          // HID/64 = 48 K-steps
    const int kn = (t + 1 < 48 ? t + 1 : 47) * 64;
    STAGE_E2(p ^ 1, kn)
    asm volatile("s_waitcnt vmcnt(6)" ::: "memory");
    __builtin_amdgcn_s_barrier();
#pragma unroll
    for (int h = 0; h < 2; ++h) {
      s16x8 af[4], bfr[2];
#pragma unroll
      for (int i = 0; i < 4; ++i)
        af[i] = *(s16x8*)(&As[p][(wr + i * 16 + l16) * 64 + (((quad + 4 * h) ^ swz) << 3)]);
#pragma unroll
      for (int j = 0; j < 2; ++j)
        bfr[j] = *(s16x8*)(&Bs[p][(wc + j * 16 + l16) * 64 + (((quad + 4 * h) ^ swz) << 3)]);
#pragma unroll
      for (int i = 0; i < 4; ++i)
#pragma unroll
        for (int j = 0; j < 2; ++j)
          acc[i][j] = __builtin_amdgcn_mfma_f32_16x16x32_bf16(af[i], bfr[j], acc[i][j], 0, 0, 0);
    }
    asm volatile("s_waitcnt lgkmcnt(0)" ::: "memory");
    __builtin_amdgcn_s_barrier();
    p ^= 1;
  }
#undef STAGE_E2
#pragma unroll
  for (int i = 0; i < 4; ++i) {
#pragma unroll
    for (int r = 0; r < 4; ++r) {
      int rl = wr + i * 16 + quad * 4 + r;
      if (lt * 128 + rl >= cnte) continue;
      int tok = stok[rl];
      float g = gate[tok];
#pragma unroll
      for (int j = 0; j < 2; ++j) {
        int col = bn + wc + j * 16 + l16;
        float val = acc[i][j][r] + b2[e * DD + col];
        out[(size_t)tok * DD + col] = x1[(size_t)tok * DD + col] + g * val;
      }
    }
  }
}

extern "C" void kernel_launch(void* const* d_in, const int* in_sizes, int n_in,
                              void* d_out, int out_size, void* d_ws, size_t ws_size,
                              hipStream_t stream) {
  const float* x     = (const float*)d_in[0];
  const float* ln1_w = (const float*)d_in[1];
  const float* ln1_b = (const float*)d_in[2];
  const float* wq    = (const float*)d_in[3];
  const float* bq    = (const float*)d_in[4];
  const float* wk    = (const float*)d_in[5];
  const float* bk    = (const float*)d_in[6];
  const float* wv    = (const float*)d_in[7];
  const float* bv    = (const float*)d_in[8];
  const float* wo    = (const float*)d_in[9];
  const float* bo    = (const float*)d_in[10];
  const float* ln2_w = (const float*)d_in[11];
  const float* ln2_b = (const float*)d_in[12];
  const float* wg    = (const float*)d_in[13];
  const float* bg    = (const float*)d_in[14];
  const float* w1    = (const float*)d_in[15];
  const float* b1    = (const float*)d_in[16];
  const float* w2    = (const float*)d_in[17];
  const float* b2    = (const float*)d_in[18];
  float* out = (float*)d_out;
  float* ws = (float*)d_ws;

  const size_t TD = (size_t)TT * DD;
  float* x1    = ws;                 // [TT,DD] fp32 (attn residual out)
  short* tlnbf = (short*)(ws + TD);  // [TT,DD] bf16 (ln2 out, egemm1 A via perm)
  short* sbase = (short*)(ws + 2 * TD);
  short* xbf   = sbase;                         // [TT,DD]
  short* ln1bf = sbase + TD + 128 * DD;         // [TT,DD]; later reused as attbf
  short* attbf = ln1bf;                         // alias (ln1bf dead after QKV)
  short* qbf   = ln1bf + TD;                    // [TT,DD]
  short* kvbf  = qbf + TD;                      // [TT,KVSTR]
  short* hbuf  = kvbf + (size_t)TT * KVSTR;     // [(TT+128),HID]
  short* wqT   = hbuf + (size_t)(TT + 128) * HID;
  short* kvT   = wqT + (size_t)DD * DD;         // contiguous after wqT (kT then vT)
  short* woT   = kvT + (size_t)KVSTR * DD;      // = wqT + 3*DD*DD
  short* w1T   = woT + (size_t)DD * DD;
  short* w2T   = w1T + (size_t)EE * DD * HID;
  int*   meta  = (int*)(w2T + (size_t)EE * HID * DD);
  int*   idx   = meta;
  float* gate  = (float*)(meta + TT);
  int*   perm  = meta + 2 * TT;
  int*   cnt2  = meta + 3 * TT;                 // [NBANK][16] histogram
  int*   cur2  = cnt2 + NBANK * 16;             // [NBANK][16] scatter cursors
  int*   bankbase = cur2 + NBANK * 16;          // [NBANK][EE]
  int*   cnt   = bankbase + NBANK * EE;         // [EE] totals
  int*   off   = cnt + 8;
  int*   tb    = off + 9;
  float* wgT   = (float*)(tb + 9);              // [EE][DD] fp32

  hipMemsetAsync(cnt2, 0, 2 * NBANK * 16 * sizeof(int), stream);

  // weight transposes (fp32 -> bf16 [N,K]); wqT/kT/vT/woT in one launch
  transpose4_bf16<<<dim3(12, 12, 4), 256, 0, stream>>>(wq, wk, wv, wo, wqT);
  transpose_bf16<<<dim3(12, 48, 8), 256, 0, stream>>>(w1, w1T, DD, HID);
  transpose_bf16<<<dim3(48, 12, 8), 256, 0, stream>>>(w2, w2T, HID, DD);
  gate_transpose<<<8, 256, 0, stream>>>(wg, wgT);

  fused_cvt_ln1<<<TT / 4, 256, 0, stream>>>(x, ln1_w, ln1_b, xbf, ln1bf);

  qkv_mgemm<<<8 * 8 * 18, 256, 0, stream>>>(ln1bf, xbf, wqT, kvT, bq, bk, bv, qbf, kvbf);

  attn_mfma<<<dim3(SS / 64, BB, HH), 256, 0, stream>>>(qbf, kvbf, kvbf + DD, attbf);

  mgemm<1, 0, 64><<<64 * 12, 256, 0, stream>>>(attbf, woT, bo, nullptr, x, x1, DD, DD);

  fused_ln2_route<<<TT / 4, 256, 0, stream>>>(x1, ln2_w, ln2_b, wgT, bg,
                                              tlnbf, idx, gate, cnt2);
  prefix2_kernel<<<1, 64, 0, stream>>>(cnt2, cnt, off, tb, bankbase);
  scatter_kernel<<<TT / 256, 256, 0, stream>>>(idx, bankbase, cur2, perm);

  egemm1<<<8 * 9 * 24, 256, 0, stream>>>(tlnbf, w1T, b1, off, tb, cnt, perm, hbuf);
  egemm2<<<8 * 9 * 12, 256, 0, stream>>>(hbuf, w2T, b2, perm, off, tb, cnt, gate, x1, out);
}

// Round 9
// 567.912 us; speedup vs baseline: 1.0563x; 1.0563x over previous
//
#include <hip/hip_runtime.h>
#include <math.h>

#define SS 512
#define BB 16
#define DD 768
#define HH 12
#define HDIM 64
#define EE 8
#define HID 3072
#define TT 8192   // SS*BB tokens
#define EPSV 1e-5f
#define KVSTR 1536
#define ASTR 72   // attention LDS row stride in shorts (144 B, 16B-aligned)
#define NBANK 64  // routing histogram banks

typedef __attribute__((ext_vector_type(8))) short s16x8;
typedef __attribute__((ext_vector_type(4))) short s16x4;
typedef __attribute__((ext_vector_type(4))) float f32x4;

__device__ inline short f2bf(float f) {
  unsigned u = __builtin_bit_cast(unsigned, f);
  unsigned r = (u + 0x7fffu + ((u >> 16) & 1u)) >> 16;
  return (short)r;
}

// tanh-form GELU (max abs err ~3e-4, invisible under bf16 pipeline noise)
__device__ inline float gelu_f(float x) {
  float y = 0.7978845608028654f * (x + 0.044715f * x * x * x);
  float e = __expf(2.f * y);
  float t = 1.f - 2.f / (e + 1.f);
  return 0.5f * x * (1.f + t);
}

// async global->LDS DMA, 16B per lane; LDS dest = wave-uniform base + lane*16
__device__ inline void gl2lds16(const void* g, void* l) {
  __builtin_amdgcn_global_load_lds(
      (const __attribute__((address_space(1))) unsigned int*)g,
      (__attribute__((address_space(3))) unsigned int*)l, 16, 0, 0);
}

// ---------------- 4x DxD transpose + convert in one launch ----------------
__global__ __launch_bounds__(256) void transpose4_bf16(const float* __restrict__ w0,
    const float* __restrict__ w1p, const float* __restrict__ w2p,
    const float* __restrict__ w3p, short* __restrict__ dst) {
  const int z = blockIdx.z;
  const float* W = (z == 0) ? w0 : (z == 1) ? w1p : (z == 2) ? w2p : w3p;
  short* Wt = dst + (size_t)z * DD * DD;
  int k0 = blockIdx.x * 64, n0 = blockIdx.y * 64;
  __shared__ float t[64][65];
  for (int i = threadIdx.x; i < 1024; i += 256) {
    int r = i >> 4, c4 = (i & 15) << 2;
    const float4 v = *(const float4*)(W + (size_t)(k0 + r) * DD + n0 + c4);
    t[r][c4] = v.x; t[r][c4 + 1] = v.y; t[r][c4 + 2] = v.z; t[r][c4 + 3] = v.w;
  }
  __syncthreads();
  for (int i = threadIdx.x; i < 1024; i += 256) {
    int r = i >> 4, c4 = (i & 15) << 2;
    s16x4 sv;
    sv.x = f2bf(t[c4][r]);     sv.y = f2bf(t[c4 + 1][r]);
    sv.z = f2bf(t[c4 + 2][r]); sv.w = f2bf(t[c4 + 3][r]);
    *(s16x4*)(Wt + (size_t)(n0 + r) * DD + k0 + c4) = sv;
  }
}

// ---------------- transpose + convert: W[K,N] fp32 -> Wt[N,K] bf16 ----------------
__global__ __launch_bounds__(256) void transpose_bf16(const float* __restrict__ W,
    short* __restrict__ Wt, int K, int N) {
  const float* Wz = W + (size_t)blockIdx.z * K * N;
  short* Wtz = Wt + (size_t)blockIdx.z * K * N;
  int k0 = blockIdx.x * 64, n0 = blockIdx.y * 64;
  __shared__ float t[64][65];
  for (int i = threadIdx.x; i < 1024; i += 256) {
    int r = i >> 4, c4 = (i & 15) << 2;
    const float4 v = *(const float4*)(Wz + (size_t)(k0 + r) * N + n0 + c4);
    t[r][c4] = v.x; t[r][c4 + 1] = v.y; t[r][c4 + 2] = v.z; t[r][c4 + 3] = v.w;
  }
  __syncthreads();
  for (int i = threadIdx.x; i < 1024; i += 256) {
    int r = i >> 4, c4 = (i & 15) << 2;
    s16x4 sv;
    sv.x = f2bf(t[c4][r]);     sv.y = f2bf(t[c4 + 1][r]);
    sv.z = f2bf(t[c4 + 2][r]); sv.w = f2bf(t[c4 + 3][r]);
    *(s16x4*)(Wtz + (size_t)(n0 + r) * K + k0 + c4) = sv;
  }
}

// ---------------- gating weight transpose: wg[D,E] fp32 -> wgT[E,D] fp32 ----------
__global__ __launch_bounds__(256) void gate_transpose(const float* __restrict__ wg,
    float* __restrict__ wgT) {
  for (int i = threadIdx.x + blockIdx.x * 256; i < EE * DD; i += 256 * 8) {
    int e = i / DD, d = i - e * DD;
    wgT[i] = wg[d * EE + e];
  }
}

// ---------------- fused x->bf16 convert + LayerNorm1 (wave-per-token) ----------------
__global__ __launch_bounds__(256) void fused_cvt_ln1(const float* __restrict__ x,
    const float* __restrict__ w, const float* __restrict__ b,
    short* __restrict__ xbf, short* __restrict__ ln1bf) {
  const int tok = blockIdx.x * 4 + (threadIdx.x >> 6);
  const int lane = threadIdx.x & 63;
  const float* row = x + (size_t)tok * DD;
  const float4 v0 = *(const float4*)(row + lane * 4);
  const float4 v1 = *(const float4*)(row + 256 + lane * 4);
  const float4 v2 = *(const float4*)(row + 512 + lane * 4);
  float s = v0.x + v0.y + v0.z + v0.w + v1.x + v1.y + v1.z + v1.w
          + v2.x + v2.y + v2.z + v2.w;
  float ss = v0.x * v0.x + v0.y * v0.y + v0.z * v0.z + v0.w * v0.w
           + v1.x * v1.x + v1.y * v1.y + v1.z * v1.z + v1.w * v1.w
           + v2.x * v2.x + v2.y * v2.y + v2.z * v2.z + v2.w * v2.w;
#pragma unroll
  for (int o = 1; o < 64; o <<= 1) { s += __shfl_xor(s, o); ss += __shfl_xor(ss, o); }
  const float mean = s * (1.f / DD);
  const float inv = rsqrtf(ss * (1.f / DD) - mean * mean + EPSV);
  short* xrow = xbf + (size_t)tok * DD;
  short* lrow = ln1bf + (size_t)tok * DD;
#define LN1_CHUNK(v, off) { \
  const float4 wv = *(const float4*)(w + (off) + lane * 4); \
  const float4 bv = *(const float4*)(b + (off) + lane * 4); \
  s16x4 xa, la; \
  xa.x = f2bf(v.x); xa.y = f2bf(v.y); xa.z = f2bf(v.z); xa.w = f2bf(v.w); \
  la.x = f2bf((v.x - mean) * inv * wv.x + bv.x); \
  la.y = f2bf((v.y - mean) * inv * wv.y + bv.y); \
  la.z = f2bf((v.z - mean) * inv * wv.z + bv.z); \
  la.w = f2bf((v.w - mean) * inv * wv.w + bv.w); \
  *(s16x4*)(xrow + (off) + lane * 4) = xa; \
  *(s16x4*)(lrow + (off) + lane * 4) = la; }
  LN1_CHUNK(v0, 0)
  LN1_CHUNK(v1, 256)
  LN1_CHUNK(v2, 512)
#undef LN1_CHUNK
}

// ---------------- fused LayerNorm2 + MoE routing (wave-per-token) ----------------
__global__ __launch_bounds__(256) void fused_ln2_route(const float* __restrict__ x1,
    const float* __restrict__ w, const float* __restrict__ b,
    const float* __restrict__ wgT, const float* __restrict__ bg,
    short* __restrict__ tlnbf, int* __restrict__ idx, float* __restrict__ gate,
    int* __restrict__ cnt2) {
  const int tok = blockIdx.x * 4 + (threadIdx.x >> 6);
  const int lane = threadIdx.x & 63;
  const float* row = x1 + (size_t)tok * DD;
  const float4 v0 = *(const float4*)(row + lane * 4);
  const float4 v1 = *(const float4*)(row + 256 + lane * 4);
  const float4 v2 = *(const float4*)(row + 512 + lane * 4);
  float s = v0.x + v0.y + v0.z + v0.w + v1.x + v1.y + v1.z + v1.w
          + v2.x + v2.y + v2.z + v2.w;
  float ss = v0.x * v0.x + v0.y * v0.y + v0.z * v0.z + v0.w * v0.w
           + v1.x * v1.x + v1.y * v1.y + v1.z * v1.z + v1.w * v1.w
           + v2.x * v2.x + v2.y * v2.y + v2.z * v2.z + v2.w * v2.w;
#pragma unroll
  for (int o = 1; o < 64; o <<= 1) { s += __shfl_xor(s, o); ss += __shfl_xor(ss, o); }
  const float mean = s * (1.f / DD);
  const float inv = rsqrtf(ss * (1.f / DD) - mean * mean + EPSV);
  short* srow = tlnbf + (size_t)tok * DD;
  float acc[EE];
#pragma unroll
  for (int e = 0; e < EE; ++e) acc[e] = 0.f;
#define LN2_CHUNK(v, off) { \
  const float4 wv = *(const float4*)(w + (off) + lane * 4); \
  const float4 bv = *(const float4*)(b + (off) + lane * 4); \
  float4 n; \
  n.x = (v.x - mean) * inv * wv.x + bv.x; \
  n.y = (v.y - mean) * inv * wv.y + bv.y; \
  n.z = (v.z - mean) * inv * wv.z + bv.z; \
  n.w = (v.w - mean) * inv * wv.w + bv.w; \
  s16x4 sv; sv.x = f2bf(n.x); sv.y = f2bf(n.y); sv.z = f2bf(n.z); sv.w = f2bf(n.w); \
  *(s16x4*)(srow + (off) + lane * 4) = sv; \
  const int i0 = (off) + lane * 4; \
  _Pragma("unroll") \
  for (int e = 0; e < EE; ++e) { \
    const float4 g = *(const float4*)(wgT + (size_t)e * DD + i0); \
    acc[e] += n.x * g.x + n.y * g.y + n.z * g.z + n.w * g.w; } }
  LN2_CHUNK(v0, 0)
  LN2_CHUNK(v1, 256)
  LN2_CHUNK(v2, 512)
#undef LN2_CHUNK
#pragma unroll
  for (int o = 1; o < 64; o <<= 1)
#pragma unroll
    for (int e = 0; e < EE; ++e) acc[e] += __shfl_xor(acc[e], o);
  if (lane == 0) {
#pragma unroll
    for (int e = 0; e < EE; ++e) acc[e] += bg[e];
    int best = 0; float bm = acc[0];
#pragma unroll
    for (int e = 1; e < EE; ++e) if (acc[e] > bm) { bm = acc[e]; best = e; }
    float sum = 0.f;
#pragma unroll
    for (int e = 0; e < EE; ++e) sum += __expf(acc[e] - bm);
    idx[tok] = best;
    gate[tok] = 1.0f / sum;
    atomicAdd(&cnt2[(blockIdx.x & (NBANK - 1)) * 16 + best], 1);
  }
}

// ---------------- prefix over banked histogram (1 wave) ----------------
__global__ void prefix2_kernel(const int* __restrict__ cnt2, int* __restrict__ cnt,
                               int* __restrict__ off, int* __restrict__ tb,
                               int* __restrict__ bankbase) {
  const int lane = threadIdx.x;   // 64 threads, 1 wave
  int c[EE], excl[EE], tot[EE];
#pragma unroll
  for (int e = 0; e < EE; ++e) c[e] = cnt2[lane * 16 + e];
#pragma unroll
  for (int e = 0; e < EE; ++e) {
    int x = c[e];
#pragma unroll
    for (int o = 1; o < 64; o <<= 1) {
      int y = __shfl_up(x, o);
      if (lane >= o) x += y;
    }
    excl[e] = x - c[e];
    tot[e] = __shfl(x, 63);
  }
  int oo = 0;
  int offl[EE];
#pragma unroll
  for (int e = 0; e < EE; ++e) { offl[e] = oo; oo += tot[e]; }
#pragma unroll
  for (int e = 0; e < EE; ++e)
    bankbase[lane * EE + e] = offl[e] + excl[e];
  if (lane == 0) {
    int o = 0, t = 0;
    for (int e = 0; e < EE; ++e) {
      off[e] = o; tb[e] = t; cnt[e] = tot[e];
      o += tot[e]; t += (tot[e] + 127) >> 7;
    }
    off[EE] = o; tb[EE] = t;
  }
}

// ---------------- scatter via banked cursors (low-contention atomics) ----------
__global__ __launch_bounds__(256) void scatter_kernel(const int* __restrict__ idx,
    const int* __restrict__ bankbase, int* __restrict__ cur2, int* __restrict__ perm) {
  int t = blockIdx.x * 256 + threadIdx.x;
  if (t < TT) {
    int e = idx[t];
    int bank = (t >> 2) & (NBANK - 1);
    int p = atomicAdd(&cur2[bank * 16 + e], 1);
    perm[bankbase[bank * EE + e] + p] = t;
  }
}

// ---------------- bf16 MFMA GEMM, DMA staging + XOR-swizzled LDS (BK=32) --------
template<int MODE, int OUTBF, int COLS>
__global__ __launch_bounds__(256) void mgemm(const short* __restrict__ A,
    const short* __restrict__ Wt, const float* __restrict__ bias,
    const float* __restrict__ bias2, const float* __restrict__ res,
    void* __restrict__ C, int N, int K) {
  const int bx = blockIdx.x;
  const int lid = bx >> 3;
  const int colt = lid >> 3, rband = lid & 7;
  const int bm = (((bx & 7) << 3) + rband) * 128;
  const int bn = colt * COLS;
  constexpr int NJ = COLS / 32;
  __shared__ short As[128 * 32];
  __shared__ short Bs[COLS * 32];
  const int tid = threadIdx.x;
  const int wave = tid >> 6, lane = tid & 63;
  const int wr = (wave >> 1) * 64, wc = (wave & 1) * (COLS / 2);
  const int l16 = lane & 15, quad = lane >> 4;
  const int kq = (((lane & 3) ^ ((lane >> 3) & 3)) << 3);
  const int sw = ((l16 >> 1) & 3);
  const short* Ab = A + (size_t)(bm + (wave << 5) + (lane >> 2)) * K + kq;
  const short* Bb = Wt + (size_t)(bn + wave * (COLS / 4) + (lane >> 2)) * K + kq;
  short* lA = &As[(wave << 5) * 32];
  short* lB = &Bs[wave * (COLS / 4) * 32];
  f32x4 acc[4][NJ] = {};
  for (int k0 = 0; k0 < K; k0 += 32) {
    gl2lds16(Ab + k0, lA);
    gl2lds16(Ab + (size_t)16 * K + k0, lA + 512);
    gl2lds16(Bb + k0, lB);
    if (COLS == 128) gl2lds16(Bb + (size_t)16 * K + k0, lB + 512);
    __syncthreads();
    s16x8 af[4], bfr[NJ];
#pragma unroll
    for (int i = 0; i < 4; ++i)
      af[i] = *(s16x8*)(&As[(wr + i * 16 + l16) * 32 + ((quad ^ sw) << 3)]);
#pragma unroll
    for (int j = 0; j < NJ; ++j)
      bfr[j] = *(s16x8*)(&Bs[(wc + j * 16 + l16) * 32 + ((quad ^ sw) << 3)]);
#pragma unroll
    for (int i = 0; i < 4; ++i)
#pragma unroll
      for (int j = 0; j < NJ; ++j)
        acc[i][j] = __builtin_amdgcn_mfma_f32_16x16x32_bf16(af[i], bfr[j], acc[i][j], 0, 0, 0);
    __syncthreads();
  }
#pragma unroll
  for (int i = 0; i < 4; ++i) {
#pragma unroll
    for (int r = 0; r < 4; ++r) {
      int row = bm + wr + i * 16 + quad * 4 + r;
#pragma unroll
      for (int j = 0; j < NJ; ++j) {
        int col = bn + wc + j * 16 + l16;
        float bv = (MODE == 2) ? (col >= DD ? bias2[col - DD] : bias[col]) : bias[col];
        float val = acc[i][j][r] + bv;
        if (MODE == 1) val += res[(size_t)row * N + col];
        if (OUTBF) ((short*)C)[(size_t)row * N + col] = f2bf(val);
        else       ((float*)C)[(size_t)row * N + col] = val;
      }
    }
  }
}

// ---------------- merged Q-proj + KV-proj (one launch, 1152 blocks) ----------------
__global__ __launch_bounds__(256) void qkv_mgemm(const short* __restrict__ ln1bf,
    const short* __restrict__ xbf, const short* __restrict__ wqT,
    const short* __restrict__ kvT, const float* __restrict__ bq,
    const float* __restrict__ bk, const float* __restrict__ bv,
    short* __restrict__ qbf, short* __restrict__ kvbf) {
  const int bx = blockIdx.x;
  const int lid = bx >> 3;
  const int colt = lid >> 3, rband = lid & 7;   // colt in [0,18)
  const int bm = (((bx & 7) << 3) + rband) * 128;
  const bool isQ = (colt < 6);
  const int bn = isQ ? colt * 128 : (colt - 6) * 128;
  const short* A  = isQ ? ln1bf : xbf;
  const short* Bt = isQ ? wqT : kvT;
  const float* bias = isQ ? bq : (bn < DD ? bk : bv);
  const int bofs = (!isQ && bn >= DD) ? DD : 0;
  short* out = isQ ? qbf : kvbf;
  const int OS = isQ ? DD : KVSTR;
  const int K = DD;
  __shared__ short As[128 * 32];
  __shared__ short Bs[128 * 32];
  const int tid = threadIdx.x;
  const int wave = tid >> 6, lane = tid & 63;
  const int wr = (wave >> 1) * 64, wc = (wave & 1) * 64;
  const int l16 = lane & 15, quad = lane >> 4;
  const int kq = (((lane & 3) ^ ((lane >> 3) & 3)) << 3);
  const int sw = ((l16 >> 1) & 3);
  const short* Ab = A + (size_t)(bm + (wave << 5) + (lane >> 2)) * K + kq;
  const short* Bb = Bt + (size_t)(bn + (wave << 5) + (lane >> 2)) * K + kq;
  short* lA = &As[(wave << 5) * 32];
  short* lB = &Bs[(wave << 5) * 32];
  f32x4 acc[4][4] = {};
  for (int k0 = 0; k0 < K; k0 += 32) {
    gl2lds16(Ab + k0, lA);
    gl2lds16(Ab + (size_t)16 * K + k0, lA + 512);
    gl2lds16(Bb + k0, lB);
    gl2lds16(Bb + (size_t)16 * K + k0, lB + 512);
    __syncthreads();
    s16x8 af[4], bfr[4];
#pragma unroll
    for (int i = 0; i < 4; ++i)
      af[i] = *(s16x8*)(&As[(wr + i * 16 + l16) * 32 + ((quad ^ sw) << 3)]);
#pragma unroll
    for (int j = 0; j < 4; ++j)
      bfr[j] = *(s16x8*)(&Bs[(wc + j * 16 + l16) * 32 + ((quad ^ sw) << 3)]);
#pragma unroll
    for (int i = 0; i < 4; ++i)
#pragma unroll
      for (int j = 0; j < 4; ++j)
        acc[i][j] = __builtin_amdgcn_mfma_f32_16x16x32_bf16(af[i], bfr[j], acc[i][j], 0, 0, 0);
    __syncthreads();
  }
#pragma unroll
  for (int i = 0; i < 4; ++i) {
#pragma unroll
    for (int r = 0; r < 4; ++r) {
      int row = bm + wr + i * 16 + quad * 4 + r;
#pragma unroll
      for (int j = 0; j < 4; ++j) {
        int col = bn + wc + j * 16 + l16;
        float val = acc[i][j][r] + bias[col - bofs];
        out[(size_t)row * OS + col] = f2bf(val);
      }
    }
  }
}

// ---------------- flash attention, bf16 MFMA, bf16 IO ----------------
__global__ __launch_bounds__(256) void attn_mfma(const short* __restrict__ q,
    const short* __restrict__ k, const short* __restrict__ v, short* __restrict__ o) {
  const int qt = blockIdx.x, bidx = blockIdx.y, hidx = blockIdx.z;
  const int tid = threadIdx.x;
  const int wave = tid >> 6, lane = tid & 63;
  const int l16 = lane & 15, quad = lane >> 4;
  const int s0 = qt * 64;
  __shared__ short Qs[64 * ASTR];
  __shared__ short Ks[64 * ASTR];
  __shared__ short Vs[64 * ASTR];   // transposed: Vs[d][key]
  __shared__ short Ps[64 * ASTR];
  for (int i = tid; i < 512; i += 256) {
    int r = i >> 3, c8 = i & 7;
    *(s16x8*)(&Qs[r * ASTR + c8 * 8]) =
        *(const s16x8*)(q + ((size_t)(s0 + r) * BB + bidx) * DD + hidx * HDIM + c8 * 8);
  }
  __syncthreads();
  s16x8 af0 = *(s16x8*)(&Qs[(wave * 16 + l16) * ASTR + quad * 8]);
  s16x8 af1 = *(s16x8*)(&Qs[(wave * 16 + l16) * ASTR + 32 + quad * 8]);
  f32x4 oacc[4] = {};
  float mr[4], lr[4];
#pragma unroll
  for (int r = 0; r < 4; ++r) { mr[r] = -1e30f; lr[r] = 0.f; }

  for (int t0 = 0; t0 < SS; t0 += 64) {
    __syncthreads();
    for (int i = tid; i < 512; i += 256) {
      int r = i >> 3, c8 = i & 7;
      *(s16x8*)(&Ks[r * ASTR + c8 * 8]) =
          *(const s16x8*)(k + ((size_t)(t0 + r) * BB + bidx) * KVSTR + hidx * HDIM + c8 * 8);
    }
    for (int i = tid; i < 1024; i += 256) {
      int r = i >> 4, c4 = i & 15;
      s16x4 vv = *(const s16x4*)(v + ((size_t)(t0 + r) * BB + bidx) * KVSTR + hidx * HDIM + c4 * 4);
      Vs[(c4 * 4 + 0) * ASTR + r] = vv.x;
      Vs[(c4 * 4 + 1) * ASTR + r] = vv.y;
      Vs[(c4 * 4 + 2) * ASTR + r] = vv.z;
      Vs[(c4 * 4 + 3) * ASTR + r] = vv.w;
    }
    __syncthreads();
    f32x4 sc[4];
    const f32x4 zero = {};
#pragma unroll
    for (int j = 0; j < 4; ++j) {
      s16x8 kf0 = *(s16x8*)(&Ks[(j * 16 + l16) * ASTR + quad * 8]);
      s16x8 kf1 = *(s16x8*)(&Ks[(j * 16 + l16) * ASTR + 32 + quad * 8]);
      sc[j] = __builtin_amdgcn_mfma_f32_16x16x32_bf16(af0, kf0, zero, 0, 0, 0);
      sc[j] = __builtin_amdgcn_mfma_f32_16x16x32_bf16(af1, kf1, sc[j], 0, 0, 0);
#pragma unroll
      for (int r = 0; r < 4; ++r) sc[j][r] *= 0.125f;
    }
    float tm[4], alpha[4], rs[4];
#pragma unroll
    for (int r = 0; r < 4; ++r) {
      tm[r] = mr[r];
#pragma unroll
      for (int j = 0; j < 4; ++j) tm[r] = fmaxf(tm[r], sc[j][r]);
    }
#pragma unroll
    for (int mask = 1; mask < 16; mask <<= 1)
#pragma unroll
      for (int r = 0; r < 4; ++r) tm[r] = fmaxf(tm[r], __shfl_xor(tm[r], mask));
#pragma unroll
    for (int r = 0; r < 4; ++r) { alpha[r] = __expf(mr[r] - tm[r]); mr[r] = tm[r]; rs[r] = 0.f; }
#pragma unroll
    for (int j = 0; j < 4; ++j)
#pragma unroll
      for (int r = 0; r < 4; ++r) {
        float p = __expf(sc[j][r] - tm[r]);
        sc[j][r] = p; rs[r] += p;
      }
#pragma unroll
    for (int mask = 1; mask < 16; mask <<= 1)
#pragma unroll
      for (int r = 0; r < 4; ++r) rs[r] += __shfl_xor(rs[r], mask);
#pragma unroll
    for (int r = 0; r < 4; ++r) lr[r] = lr[r] * alpha[r] + rs[r];
#pragma unroll
    for (int j = 0; j < 4; ++j)
#pragma unroll
      for (int r = 0; r < 4; ++r)
        Ps[(wave * 16 + quad * 4 + r) * ASTR + j * 16 + l16] = f2bf(sc[j][r]);
#pragma unroll
    for (int jd = 0; jd < 4; ++jd)
#pragma unroll
      for (int r = 0; r < 4; ++r) oacc[jd][r] *= alpha[r];
    __syncthreads();
    s16x8 pf0 = *(s16x8*)(&Ps[(wave * 16 + l16) * ASTR + quad * 8]);
    s16x8 pf1 = *(s16x8*)(&Ps[(wave * 16 + l16) * ASTR + 32 + quad * 8]);
#pragma unroll
    for (int jd = 0; jd < 4; ++jd) {
      s16x8 vf0 = *(s16x8*)(&Vs[(jd * 16 + l16) * ASTR + quad * 8]);
      s16x8 vf1 = *(s16x8*)(&Vs[(jd * 16 + l16) * ASTR + 32 + quad * 8]);
      oacc[jd] = __builtin_amdgcn_mfma_f32_16x16x32_bf16(pf0, vf0, oacc[jd], 0, 0, 0);
      oacc[jd] = __builtin_amdgcn_mfma_f32_16x16x32_bf16(pf1, vf1, oacc[jd], 0, 0, 0);
    }
  }
#pragma unroll
  for (int r = 0; r < 4; ++r) {
    int row = s0 + wave * 16 + quad * 4 + r;
    float invl = 1.f / lr[r];
#pragma unroll
    for (int jd = 0; jd < 4; ++jd) {
      int d = jd * 16 + l16;
      o[((size_t)row * BB + bidx) * DD + hidx * HDIM + d] = f2bf(oacc[jd][r] * invl);
    }
  }
}

// ---------------- expert GEMM 1 (BK=32, single-buf): h = gelu(tln[perm]@w1[e]) ----
// Best-measured config (round 4): 16 KB LDS -> high occupancy; simple 2-barrier.
__global__ __launch_bounds__(256) void egemm1(const short* __restrict__ tlnbf,
    const short* __restrict__ w1t, const float* __restrict__ b1,
    const int* __restrict__ off, const int* __restrict__ tb, const int* __restrict__ cnt,
    const int* __restrict__ perm, short* __restrict__ hbuf) {
  const int bx = blockIdx.x;
  const int lid = bx >> 3;
  const int rband = lid % 9, colt = lid / 9;
  const int row = (bx & 7) * 9 + rband;
  if (row >= tb[EE]) return;
  int e = 0;
  while (e < EE - 1 && tb[e + 1] <= row) ++e;
  const int lt = row - tb[e];
  const int cnte = cnt[e];
  const int slot0 = off[e] + lt * 128;
  const int slast = off[e] + cnte - 1;
  const int bn = colt * 128;
  const int tid = threadIdx.x;
  const int wave = tid >> 6, lane = tid & 63;
  const int wr = (wave >> 1) * 64, wc = (wave & 1) * 64;
  const int l16 = lane & 15, quad = lane >> 4;
  const int kq = (((lane & 3) ^ ((lane >> 3) & 3)) << 3);
  const int sw = ((l16 >> 1) & 3);
  __shared__ short As[128 * 32];
  __shared__ short Bs[128 * 32];
  f32x4 acc[4][4] = {};
  const int sA = slot0 + (wave << 5) + (lane >> 2);
  const int tokA = perm[sA <= slast ? sA : slast];
  const int tokB = perm[(sA + 16) <= slast ? (sA + 16) : slast];
  const short* AbA = tlnbf + (size_t)tokA * DD + kq;
  const short* AbB = tlnbf + (size_t)tokB * DD + kq;
  const short* Bb = w1t + (size_t)e * DD * HID
                  + (size_t)(bn + (wave << 5) + (lane >> 2)) * DD + kq;
  short* lA = &As[(wave << 5) * 32];
  short* lB = &Bs[(wave << 5) * 32];
  for (int k0 = 0; k0 < DD; k0 += 32) {
    gl2lds16(AbA + k0, lA);
    gl2lds16(AbB + k0, lA + 512);
    gl2lds16(Bb + k0, lB);
    gl2lds16(Bb + (size_t)16 * DD + k0, lB + 512);
    __syncthreads();
    s16x8 af[4], bfr[4];
#pragma unroll
    for (int i = 0; i < 4; ++i)
      af[i] = *(s16x8*)(&As[(wr + i * 16 + l16) * 32 + ((quad ^ sw) << 3)]);
#pragma unroll
    for (int j = 0; j < 4; ++j)
      bfr[j] = *(s16x8*)(&Bs[(wc + j * 16 + l16) * 32 + ((quad ^ sw) << 3)]);
#pragma unroll
    for (int i = 0; i < 4; ++i)
#pragma unroll
      for (int j = 0; j < 4; ++j)
        acc[i][j] = __builtin_amdgcn_mfma_f32_16x16x32_bf16(af[i], bfr[j], acc[i][j], 0, 0, 0);
    __syncthreads();
  }
#pragma unroll
  for (int i = 0; i < 4; ++i) {
#pragma unroll
    for (int r = 0; r < 4; ++r) {
      int rl = wr + i * 16 + quad * 4 + r;
      if (lt * 128 + rl >= cnte) continue;
#pragma unroll
      for (int j = 0; j < 4; ++j) {
        int col = bn + wc + j * 16 + l16;
        float xv = acc[i][j][r] + b1[e * HID + col];
        hbuf[(size_t)(slot0 + rl) * HID + col] = f2bf(gelu_f(xv));
      }
    }
  }
}

// ---------------- expert GEMM 2 (BK=64, 128x64, single-buf) ----------------------
// Best-measured config (round 5): 24.5 KB LDS, K=3072 at 48 barrier steps.
__global__ __launch_bounds__(256) void egemm2(const short* __restrict__ hbuf,
    const short* __restrict__ w2t, const float* __restrict__ b2,
    const int* __restrict__ perm, const int* __restrict__ off,
    const int* __restrict__ tb, const int* __restrict__ cnt,
    const float* __restrict__ gate, const float* __restrict__ x1,
    float* __restrict__ out) {
  const int bx = blockIdx.x;
  const int lid = bx >> 3;
  const int colt = lid % 12, rband = lid / 12;
  const int row = (bx & 7) * 9 + rband;
  if (row >= tb[EE]) return;
  int e = 0;
  while (e < EE - 1 && tb[e + 1] <= row) ++e;
  const int lt = row - tb[e];
  const int cnte = cnt[e];
  const int slot0 = off[e] + lt * 128;
  const int bn = colt * 64;
  const int tid = threadIdx.x;
  const int wave = tid >> 6, lane = tid & 63;
  const int wr = (wave >> 1) * 64, wc = (wave & 1) * 32;
  const int l16 = lane & 15, quad = lane >> 4;
  const int rg = lane >> 3;
  const int kq8 = (((lane & 7) ^ rg) << 3);
  const int swz = l16 & 7;
  __shared__ short As[128 * 64];
  __shared__ short Bs[64 * 64];
  __shared__ int stok[128];
  if (tid < 128) stok[tid] = (lt * 128 + tid < cnte) ? perm[slot0 + tid] : -1;
  f32x4 acc[4][2] = {};
  const short* Ab = hbuf + (size_t)(slot0 + (wave << 5) + rg) * HID + kq8;
  const short* Bb = w2t + (size_t)e * HID * DD
                  + (size_t)(bn + wave * 16 + rg) * HID + kq8;
  short* lA = &As[(wave << 5) * 64];
  short* lB = &Bs[wave * 16 * 64];
  for (int k0 = 0; k0 < HID; k0 += 64) {
    gl2lds16(Ab + k0, lA);
    gl2lds16(Ab + (size_t)8 * HID + k0, lA + 512);
    gl2lds16(Ab + (size_t)16 * HID + k0, lA + 1024);
    gl2lds16(Ab + (size_t)24 * HID + k0, lA + 1536);
    gl2lds16(Bb + k0, lB);
    gl2lds16(Bb + (size_t)8 * HID + k0, lB + 512);
    __syncthreads();
#pragma unroll
    for (int h = 0; h < 2; ++h) {
      s16x8 af[4], bfr[2];
#pragma unroll
      for (int i = 0; i < 4; ++i)
        af[i] = *(s16x8*)(&As[(wr + i * 16 + l16) * 64 + (((quad + 4 * h) ^ swz) << 3)]);
#pragma unroll
      for (int j = 0; j < 2; ++j)
        bfr[j] = *(s16x8*)(&Bs[(wc + j * 16 + l16) * 64 + (((quad + 4 * h) ^ swz) << 3)]);
#pragma unroll
      for (int i = 0; i < 4; ++i)
#pragma unroll
        for (int j = 0; j < 2; ++j)
          acc[i][j] = __builtin_amdgcn_mfma_f32_16x16x32_bf16(af[i], bfr[j], acc[i][j], 0, 0, 0);
    }
    __syncthreads();
  }
#pragma unroll
  for (int i = 0; i < 4; ++i) {
#pragma unroll
    for (int r = 0; r < 4; ++r) {
      int rl = wr + i * 16 + quad * 4 + r;
      if (lt * 128 + rl >= cnte) continue;
      int tok = stok[rl];
      float g = gate[tok];
#pragma unroll
      for (int j = 0; j < 2; ++j) {
        int col = bn + wc + j * 16 + l16;
        float val = acc[i][j][r] + b2[e * DD + col];
        out[(size_t)tok * DD + col] = x1[(size_t)tok * DD + col] + g * val;
      }
    }
  }
}

extern "C" void kernel_launch(void* const* d_in, const int* in_sizes, int n_in,
                              void* d_out, int out_size, void* d_ws, size_t ws_size,
                              hipStream_t stream) {
  const float* x     = (const float*)d_in[0];
  const float* ln1_w = (const float*)d_in[1];
  const float* ln1_b = (const float*)d_in[2];
  const float* wq    = (const float*)d_in[3];
  const float* bq    = (const float*)d_in[4];
  const float* wk    = (const float*)d_in[5];
  const float* bk    = (const float*)d_in[6];
  const float* wv    = (const float*)d_in[7];
  const float* bv    = (const float*)d_in[8];
  const float* wo    = (const float*)d_in[9];
  const float* bo    = (const float*)d_in[10];
  const float* ln2_w = (const float*)d_in[11];
  const float* ln2_b = (const float*)d_in[12];
  const float* wg    = (const float*)d_in[13];
  const float* bg    = (const float*)d_in[14];
  const float* w1    = (const float*)d_in[15];
  const float* b1    = (const float*)d_in[16];
  const float* w2    = (const float*)d_in[17];
  const float* b2    = (const float*)d_in[18];
  float* out = (float*)d_out;
  float* ws = (float*)d_ws;

  const size_t TD = (size_t)TT * DD;
  float* x1    = ws;                 // [TT,DD] fp32 (attn residual out)
  short* tlnbf = (short*)(ws + TD);  // [TT,DD] bf16 (ln2 out, egemm1 A via perm)
  short* sbase = (short*)(ws + 2 * TD);
  short* xbf   = sbase;                         // [TT,DD]
  short* ln1bf = sbase + TD + 128 * DD;         // [TT,DD]; later reused as attbf
  short* attbf = ln1bf;                         // alias (ln1bf dead after QKV)
  short* qbf   = ln1bf + TD;                    // [TT,DD]
  short* kvbf  = qbf + TD;                      // [TT,KVSTR]
  short* hbuf  = kvbf + (size_t)TT * KVSTR;     // [(TT+128),HID]
  short* wqT   = hbuf + (size_t)(TT + 128) * HID;
  short* kvT   = wqT + (size_t)DD * DD;         // contiguous after wqT (kT then vT)
  short* woT   = kvT + (size_t)KVSTR * DD;      // = wqT + 3*DD*DD
  short* w1T   = woT + (size_t)DD * DD;
  short* w2T   = w1T + (size_t)EE * DD * HID;
  int*   meta  = (int*)(w2T + (size_t)EE * HID * DD);
  int*   idx   = meta;
  float* gate  = (float*)(meta + TT);
  int*   perm  = meta + 2 * TT;
  int*   cnt2  = meta + 3 * TT;                 // [NBANK][16] histogram
  int*   cur2  = cnt2 + NBANK * 16;             // [NBANK][16] scatter cursors
  int*   bankbase = cur2 + NBANK * 16;          // [NBANK][EE]
  int*   cnt   = bankbase + NBANK * EE;         // [EE] totals
  int*   off   = cnt + 8;
  int*   tb    = off + 9;
  float* wgT   = (float*)(tb + 9);              // [EE][DD] fp32

  hipMemsetAsync(cnt2, 0, 2 * NBANK * 16 * sizeof(int), stream);

  // weight transposes (fp32 -> bf16 [N,K]); wqT/kT/vT/woT in one launch
  transpose4_bf16<<<dim3(12, 12, 4), 256, 0, stream>>>(wq, wk, wv, wo, wqT);
  transpose_bf16<<<dim3(12, 48, 8), 256, 0, stream>>>(w1, w1T, DD, HID);
  transpose_bf16<<<dim3(48, 12, 8), 256, 0, stream>>>(w2, w2T, HID, DD);
  gate_transpose<<<8, 256, 0, stream>>>(wg, wgT);

  fused_cvt_ln1<<<TT / 4, 256, 0, stream>>>(x, ln1_w, ln1_b, xbf, ln1bf);

  qkv_mgemm<<<8 * 8 * 18, 256, 0, stream>>>(ln1bf, xbf, wqT, kvT, bq, bk, bv, qbf, kvbf);

  attn_mfma<<<dim3(SS / 64, BB, HH), 256, 0, stream>>>(qbf, kvbf, kvbf + DD, attbf);

  mgemm<1, 0, 64><<<64 * 12, 256, 0, stream>>>(attbf, woT, bo, nullptr, x, x1, DD, DD);

  fused_ln2_route<<<TT / 4, 256, 0, stream>>>(x1, ln2_w, ln2_b, wgT, bg,
                                              tlnbf, idx, gate, cnt2);
  prefix2_kernel<<<1, 64, 0, stream>>>(cnt2, cnt, off, tb, bankbase);
  scatter_kernel<<<TT / 256, 256, 0, stream>>>(idx, bankbase, cur2, perm);

  egemm1<<<8 * 9 * 24, 256, 0, stream>>>(tlnbf, w1T, b1, off, tb, cnt, perm, hbuf);
  egemm2<<<8 * 9 * 12, 256, 0, stream>>>(hbuf, w2T, b2, perm, off, tb, cnt, gate, x1, out);
}

// Round 11
// 553.564 us; speedup vs baseline: 1.0837x; 1.0259x over previous
//
#include <hip/hip_runtime.h>
#include <math.h>

#define SS 512
#define BB 16
#define DD 768
#define HH 12
#define HDIM 64
#define EE 8
#define HID 3072
#define TT 8192   // SS*BB tokens
#define EPSV 1e-5f
#define KVSTR 1536
#define ASTR 72   // attention LDS row stride in shorts (144 B, 16B-aligned)
#define NBANK 64  // routing histogram banks

typedef __attribute__((ext_vector_type(8))) short s16x8;
typedef __attribute__((ext_vector_type(4))) short s16x4;
typedef __attribute__((ext_vector_type(4))) float f32x4;

__device__ inline short f2bf(float f) {
  unsigned u = __builtin_bit_cast(unsigned, f);
  unsigned r = (u + 0x7fffu + ((u >> 16) & 1u)) >> 16;
  return (short)r;
}

// tanh-form GELU (max abs err ~3e-4, invisible under bf16 pipeline noise)
__device__ inline float gelu_f(float x) {
  float y = 0.7978845608028654f * (x + 0.044715f * x * x * x);
  float e = __expf(2.f * y);
  float t = 1.f - 2.f / (e + 1.f);
  return 0.5f * x * (1.f + t);
}

// async global->LDS DMA, 16B per lane; LDS dest = wave-uniform base + lane*16
__device__ inline void gl2lds16(const void* g, void* l) {
  __builtin_amdgcn_global_load_lds(
      (const __attribute__((address_space(1))) unsigned int*)g,
      (__attribute__((address_space(3))) unsigned int*)l, 16, 0, 0);
}

// ---------------- 4x DxD transpose + convert in one launch ----------------
__global__ __launch_bounds__(256) void transpose4_bf16(const float* __restrict__ w0,
    const float* __restrict__ w1p, const float* __restrict__ w2p,
    const float* __restrict__ w3p, short* __restrict__ dst) {
  const int z = blockIdx.z;
  const float* W = (z == 0) ? w0 : (z == 1) ? w1p : (z == 2) ? w2p : w3p;
  short* Wt = dst + (size_t)z * DD * DD;
  int k0 = blockIdx.x * 64, n0 = blockIdx.y * 64;
  __shared__ float t[64][65];
  for (int i = threadIdx.x; i < 1024; i += 256) {
    int r = i >> 4, c4 = (i & 15) << 2;
    const float4 v = *(const float4*)(W + (size_t)(k0 + r) * DD + n0 + c4);
    t[r][c4] = v.x; t[r][c4 + 1] = v.y; t[r][c4 + 2] = v.z; t[r][c4 + 3] = v.w;
  }
  __syncthreads();
  for (int i = threadIdx.x; i < 1024; i += 256) {
    int r = i >> 4, c4 = (i & 15) << 2;
    s16x4 sv;
    sv.x = f2bf(t[c4][r]);     sv.y = f2bf(t[c4 + 1][r]);
    sv.z = f2bf(t[c4 + 2][r]); sv.w = f2bf(t[c4 + 3][r]);
    *(s16x4*)(Wt + (size_t)(n0 + r) * DD + k0 + c4) = sv;
  }
}

// ---------------- transpose + convert: W[K,N] fp32 -> Wt[N,K] bf16 ----------------
__global__ __launch_bounds__(256) void transpose_bf16(const float* __restrict__ W,
    short* __restrict__ Wt, int K, int N) {
  const float* Wz = W + (size_t)blockIdx.z * K * N;
  short* Wtz = Wt + (size_t)blockIdx.z * K * N;
  int k0 = blockIdx.x * 64, n0 = blockIdx.y * 64;
  __shared__ float t[64][65];
  for (int i = threadIdx.x; i < 1024; i += 256) {
    int r = i >> 4, c4 = (i & 15) << 2;
    const float4 v = *(const float4*)(Wz + (size_t)(k0 + r) * N + n0 + c4);
    t[r][c4] = v.x; t[r][c4 + 1] = v.y; t[r][c4 + 2] = v.z; t[r][c4 + 3] = v.w;
  }
  __syncthreads();
  for (int i = threadIdx.x; i < 1024; i += 256) {
    int r = i >> 4, c4 = (i & 15) << 2;
    s16x4 sv;
    sv.x = f2bf(t[c4][r]);     sv.y = f2bf(t[c4 + 1][r]);
    sv.z = f2bf(t[c4 + 2][r]); sv.w = f2bf(t[c4 + 3][r]);
    *(s16x4*)(Wtz + (size_t)(n0 + r) * K + k0 + c4) = sv;
  }
}

// ---------------- gating weight transpose: wg[D,E] fp32 -> wgT[E,D] fp32 ----------
__global__ __launch_bounds__(256) void gate_transpose(const float* __restrict__ wg,
    float* __restrict__ wgT) {
  for (int i = threadIdx.x + blockIdx.x * 256; i < EE * DD; i += 256 * 8) {
    int e = i / DD, d = i - e * DD;
    wgT[i] = wg[d * EE + e];
  }
}

// ---------------- fused x->bf16 convert + LayerNorm1 (wave-per-token) ----------------
__global__ __launch_bounds__(256) void fused_cvt_ln1(const float* __restrict__ x,
    const float* __restrict__ w, const float* __restrict__ b,
    short* __restrict__ xbf, short* __restrict__ ln1bf) {
  const int tok = blockIdx.x * 4 + (threadIdx.x >> 6);
  const int lane = threadIdx.x & 63;
  const float* row = x + (size_t)tok * DD;
  const float4 v0 = *(const float4*)(row + lane * 4);
  const float4 v1 = *(const float4*)(row + 256 + lane * 4);
  const float4 v2 = *(const float4*)(row + 512 + lane * 4);
  float s = v0.x + v0.y + v0.z + v0.w + v1.x + v1.y + v1.z + v1.w
          + v2.x + v2.y + v2.z + v2.w;
  float ss = v0.x * v0.x + v0.y * v0.y + v0.z * v0.z + v0.w * v0.w
           + v1.x * v1.x + v1.y * v1.y + v1.z * v1.z + v1.w * v1.w
           + v2.x * v2.x + v2.y * v2.y + v2.z * v2.z + v2.w * v2.w;
#pragma unroll
  for (int o = 1; o < 64; o <<= 1) { s += __shfl_xor(s, o); ss += __shfl_xor(ss, o); }
  const float mean = s * (1.f / DD);
  const float inv = rsqrtf(ss * (1.f / DD) - mean * mean + EPSV);
  short* xrow = xbf + (size_t)tok * DD;
  short* lrow = ln1bf + (size_t)tok * DD;
#define LN1_CHUNK(v, off) { \
  const float4 wv = *(const float4*)(w + (off) + lane * 4); \
  const float4 bv = *(const float4*)(b + (off) + lane * 4); \
  s16x4 xa, la; \
  xa.x = f2bf(v.x); xa.y = f2bf(v.y); xa.z = f2bf(v.z); xa.w = f2bf(v.w); \
  la.x = f2bf((v.x - mean) * inv * wv.x + bv.x); \
  la.y = f2bf((v.y - mean) * inv * wv.y + bv.y); \
  la.z = f2bf((v.z - mean) * inv * wv.z + bv.z); \
  la.w = f2bf((v.w - mean) * inv * wv.w + bv.w); \
  *(s16x4*)(xrow + (off) + lane * 4) = xa; \
  *(s16x4*)(lrow + (off) + lane * 4) = la; }
  LN1_CHUNK(v0, 0)
  LN1_CHUNK(v1, 256)
  LN1_CHUNK(v2, 512)
#undef LN1_CHUNK
}

// ---------------- fused LayerNorm2 + MoE routing (wave-per-token) ----------------
__global__ __launch_bounds__(256) void fused_ln2_route(const float* __restrict__ x1,
    const float* __restrict__ w, const float* __restrict__ b,
    const float* __restrict__ wgT, const float* __restrict__ bg,
    short* __restrict__ tlnbf, int* __restrict__ idx, float* __restrict__ gate,
    int* __restrict__ cnt2) {
  const int tok = blockIdx.x * 4 + (threadIdx.x >> 6);
  const int lane = threadIdx.x & 63;
  const float* row = x1 + (size_t)tok * DD;
  const float4 v0 = *(const float4*)(row + lane * 4);
  const float4 v1 = *(const float4*)(row + 256 + lane * 4);
  const float4 v2 = *(const float4*)(row + 512 + lane * 4);
  float s = v0.x + v0.y + v0.z + v0.w + v1.x + v1.y + v1.z + v1.w
          + v2.x + v2.y + v2.z + v2.w;
  float ss = v0.x * v0.x + v0.y * v0.y + v0.z * v0.z + v0.w * v0.w
           + v1.x * v1.x + v1.y * v1.y + v1.z * v1.z + v1.w * v1.w
           + v2.x * v2.x + v2.y * v2.y + v2.z * v2.z + v2.w * v2.w;
#pragma unroll
  for (int o = 1; o < 64; o <<= 1) { s += __shfl_xor(s, o); ss += __shfl_xor(ss, o); }
  const float mean = s * (1.f / DD);
  const float inv = rsqrtf(ss * (1.f / DD) - mean * mean + EPSV);
  short* srow = tlnbf + (size_t)tok * DD;
  float acc[EE];
#pragma unroll
  for (int e = 0; e < EE; ++e) acc[e] = 0.f;
#define LN2_CHUNK(v, off) { \
  const float4 wv = *(const float4*)(w + (off) + lane * 4); \
  const float4 bv = *(const float4*)(b + (off) + lane * 4); \
  float4 n; \
  n.x = (v.x - mean) * inv * wv.x + bv.x; \
  n.y = (v.y - mean) * inv * wv.y + bv.y; \
  n.z = (v.z - mean) * inv * wv.z + bv.z; \
  n.w = (v.w - mean) * inv * wv.w + bv.w; \
  s16x4 sv; sv.x = f2bf(n.x); sv.y = f2bf(n.y); sv.z = f2bf(n.z); sv.w = f2bf(n.w); \
  *(s16x4*)(srow + (off) + lane * 4) = sv; \
  const int i0 = (off) + lane * 4; \
  _Pragma("unroll") \
  for (int e = 0; e < EE; ++e) { \
    const float4 g = *(const float4*)(wgT + (size_t)e * DD + i0); \
    acc[e] += n.x * g.x + n.y * g.y + n.z * g.z + n.w * g.w; } }
  LN2_CHUNK(v0, 0)
  LN2_CHUNK(v1, 256)
  LN2_CHUNK(v2, 512)
#undef LN2_CHUNK
#pragma unroll
  for (int o = 1; o < 64; o <<= 1)
#pragma unroll
    for (int e = 0; e < EE; ++e) acc[e] += __shfl_xor(acc[e], o);
  if (lane == 0) {
#pragma unroll
    for (int e = 0; e < EE; ++e) acc[e] += bg[e];
    int best = 0; float bm = acc[0];
#pragma unroll
    for (int e = 1; e < EE; ++e) if (acc[e] > bm) { bm = acc[e]; best = e; }
    float sum = 0.f;
#pragma unroll
    for (int e = 0; e < EE; ++e) sum += __expf(acc[e] - bm);
    idx[tok] = best;
    gate[tok] = 1.0f / sum;
    atomicAdd(&cnt2[(blockIdx.x & (NBANK - 1)) * 16 + best], 1);
  }
}

// ---------------- prefix over banked histogram (1 wave) ----------------
__global__ void prefix2_kernel(const int* __restrict__ cnt2, int* __restrict__ cnt,
                               int* __restrict__ off, int* __restrict__ tb,
                               int* __restrict__ bankbase) {
  const int lane = threadIdx.x;   // 64 threads, 1 wave
  int c[EE], excl[EE], tot[EE];
#pragma unroll
  for (int e = 0; e < EE; ++e) c[e] = cnt2[lane * 16 + e];
#pragma unroll
  for (int e = 0; e < EE; ++e) {
    int x = c[e];
#pragma unroll
    for (int o = 1; o < 64; o <<= 1) {
      int y = __shfl_up(x, o);
      if (lane >= o) x += y;
    }
    excl[e] = x - c[e];
    tot[e] = __shfl(x, 63);
  }
  int oo = 0;
  int offl[EE];
#pragma unroll
  for (int e = 0; e < EE; ++e) { offl[e] = oo; oo += tot[e]; }
#pragma unroll
  for (int e = 0; e < EE; ++e)
    bankbase[lane * EE + e] = offl[e] + excl[e];
  if (lane == 0) {
    int o = 0, t = 0;
    for (int e = 0; e < EE; ++e) {
      off[e] = o; tb[e] = t; cnt[e] = tot[e];
      o += tot[e]; t += (tot[e] + 127) >> 7;
    }
    off[EE] = o; tb[EE] = t;
  }
}

// ---------------- scatter via banked cursors (low-contention atomics) ----------
__global__ __launch_bounds__(256) void scatter_kernel(const int* __restrict__ idx,
    const int* __restrict__ bankbase, int* __restrict__ cur2, int* __restrict__ perm) {
  int t = blockIdx.x * 256 + threadIdx.x;
  if (t < TT) {
    int e = idx[t];
    int bank = (t >> 2) & (NBANK - 1);
    int p = atomicAdd(&cur2[bank * 16 + e], 1);
    perm[bankbase[bank * EE + e] + p] = t;
  }
}

// ---------------- bf16 MFMA GEMM, DMA staging + XOR-swizzled LDS (BK=32) --------
template<int MODE, int OUTBF, int COLS>
__global__ __launch_bounds__(256) void mgemm(const short* __restrict__ A,
    const short* __restrict__ Wt, const float* __restrict__ bias,
    const float* __restrict__ bias2, const float* __restrict__ res,
    void* __restrict__ C, int N, int K) {
  const int bx = blockIdx.x;
  const int lid = bx >> 3;
  const int colt = lid >> 3, rband = lid & 7;
  const int bm = (((bx & 7) << 3) + rband) * 128;
  const int bn = colt * COLS;
  constexpr int NJ = COLS / 32;
  __shared__ short As[128 * 32];
  __shared__ short Bs[COLS * 32];
  const int tid = threadIdx.x;
  const int wave = tid >> 6, lane = tid & 63;
  const int wr = (wave >> 1) * 64, wc = (wave & 1) * (COLS / 2);
  const int l16 = lane & 15, quad = lane >> 4;
  const int kq = (((lane & 3) ^ ((lane >> 3) & 3)) << 3);
  const int sw = ((l16 >> 1) & 3);
  const short* Ab = A + (size_t)(bm + (wave << 5) + (lane >> 2)) * K + kq;
  const short* Bb = Wt + (size_t)(bn + wave * (COLS / 4) + (lane >> 2)) * K + kq;
  short* lA = &As[(wave << 5) * 32];
  short* lB = &Bs[wave * (COLS / 4) * 32];
  f32x4 acc[4][NJ] = {};
  for (int k0 = 0; k0 < K; k0 += 32) {
    gl2lds16(Ab + k0, lA);
    gl2lds16(Ab + (size_t)16 * K + k0, lA + 512);
    gl2lds16(Bb + k0, lB);
    if (COLS == 128) gl2lds16(Bb + (size_t)16 * K + k0, lB + 512);
    __syncthreads();
    s16x8 af[4], bfr[NJ];
#pragma unroll
    for (int i = 0; i < 4; ++i)
      af[i] = *(s16x8*)(&As[(wr + i * 16 + l16) * 32 + ((quad ^ sw) << 3)]);
#pragma unroll
    for (int j = 0; j < NJ; ++j)
      bfr[j] = *(s16x8*)(&Bs[(wc + j * 16 + l16) * 32 + ((quad ^ sw) << 3)]);
#pragma unroll
    for (int i = 0; i < 4; ++i)
#pragma unroll
      for (int j = 0; j < NJ; ++j)
        acc[i][j] = __builtin_amdgcn_mfma_f32_16x16x32_bf16(af[i], bfr[j], acc[i][j], 0, 0, 0);
    __syncthreads();
  }
#pragma unroll
  for (int i = 0; i < 4; ++i) {
#pragma unroll
    for (int r = 0; r < 4; ++r) {
      int row = bm + wr + i * 16 + quad * 4 + r;
#pragma unroll
      for (int j = 0; j < NJ; ++j) {
        int col = bn + wc + j * 16 + l16;
        float bv = (MODE == 2) ? (col >= DD ? bias2[col - DD] : bias[col]) : bias[col];
        float val = acc[i][j][r] + bv;
        if (MODE == 1) val += res[(size_t)row * N + col];
        if (OUTBF) ((short*)C)[(size_t)row * N + col] = f2bf(val);
        else       ((float*)C)[(size_t)row * N + col] = val;
      }
    }
  }
}

// ---------------- merged Q-proj + KV-proj (one launch, 1152 blocks) ----------------
__global__ __launch_bounds__(256) void qkv_mgemm(const short* __restrict__ ln1bf,
    const short* __restrict__ xbf, const short* __restrict__ wqT,
    const short* __restrict__ kvT, const float* __restrict__ bq,
    const float* __restrict__ bk, const float* __restrict__ bv,
    short* __restrict__ qbf, short* __restrict__ kvbf) {
  const int bx = blockIdx.x;
  const int lid = bx >> 3;
  const int colt = lid >> 3, rband = lid & 7;   // colt in [0,18)
  const int bm = (((bx & 7) << 3) + rband) * 128;
  const bool isQ = (colt < 6);
  const int bn = isQ ? colt * 128 : (colt - 6) * 128;
  const short* A  = isQ ? ln1bf : xbf;
  const short* Bt = isQ ? wqT : kvT;
  const float* bias = isQ ? bq : (bn < DD ? bk : bv);
  const int bofs = (!isQ && bn >= DD) ? DD : 0;
  short* out = isQ ? qbf : kvbf;
  const int OS = isQ ? DD : KVSTR;
  const int K = DD;
  __shared__ short As[128 * 32];
  __shared__ short Bs[128 * 32];
  const int tid = threadIdx.x;
  const int wave = tid >> 6, lane = tid & 63;
  const int wr = (wave >> 1) * 64, wc = (wave & 1) * 64;
  const int l16 = lane & 15, quad = lane >> 4;
  const int kq = (((lane & 3) ^ ((lane >> 3) & 3)) << 3);
  const int sw = ((l16 >> 1) & 3);
  const short* Ab = A + (size_t)(bm + (wave << 5) + (lane >> 2)) * K + kq;
  const short* Bb = Bt + (size_t)(bn + (wave << 5) + (lane >> 2)) * K + kq;
  short* lA = &As[(wave << 5) * 32];
  short* lB = &Bs[(wave << 5) * 32];
  f32x4 acc[4][4] = {};
  for (int k0 = 0; k0 < K; k0 += 32) {
    gl2lds16(Ab + k0, lA);
    gl2lds16(Ab + (size_t)16 * K + k0, lA + 512);
    gl2lds16(Bb + k0, lB);
    gl2lds16(Bb + (size_t)16 * K + k0, lB + 512);
    __syncthreads();
    s16x8 af[4], bfr[4];
#pragma unroll
    for (int i = 0; i < 4; ++i)
      af[i] = *(s16x8*)(&As[(wr + i * 16 + l16) * 32 + ((quad ^ sw) << 3)]);
#pragma unroll
    for (int j = 0; j < 4; ++j)
      bfr[j] = *(s16x8*)(&Bs[(wc + j * 16 + l16) * 32 + ((quad ^ sw) << 3)]);
#pragma unroll
    for (int i = 0; i < 4; ++i)
#pragma unroll
      for (int j = 0; j < 4; ++j)
        acc[i][j] = __builtin_amdgcn_mfma_f32_16x16x32_bf16(af[i], bfr[j], acc[i][j], 0, 0, 0);
    __syncthreads();
  }
#pragma unroll
  for (int i = 0; i < 4; ++i) {
#pragma unroll
    for (int r = 0; r < 4; ++r) {
      int row = bm + wr + i * 16 + quad * 4 + r;
#pragma unroll
      for (int j = 0; j < 4; ++j) {
        int col = bn + wc + j * 16 + l16;
        float val = acc[i][j][r] + bias[col - bofs];
        out[(size_t)row * OS + col] = f2bf(val);
      }
    }
  }
}

// ---------------- flash attention, bf16 MFMA, bf16 IO ----------------
__global__ __launch_bounds__(256) void attn_mfma(const short* __restrict__ q,
    const short* __restrict__ k, const short* __restrict__ v, short* __restrict__ o) {
  const int qt = blockIdx.x, bidx = blockIdx.y, hidx = blockIdx.z;
  const int tid = threadIdx.x;
  const int wave = tid >> 6, lane = tid & 63;
  const int l16 = lane & 15, quad = lane >> 4;
  const int s0 = qt * 64;
  __shared__ short Qs[64 * ASTR];
  __shared__ short Ks[64 * ASTR];
  __shared__ short Vs[64 * ASTR];   // transposed: Vs[d][key]
  __shared__ short Ps[64 * ASTR];
  for (int i = tid; i < 512; i += 256) {
    int r = i >> 3, c8 = i & 7;
    *(s16x8*)(&Qs[r * ASTR + c8 * 8]) =
        *(const s16x8*)(q + ((size_t)(s0 + r) * BB + bidx) * DD + hidx * HDIM + c8 * 8);
  }
  __syncthreads();
  s16x8 af0 = *(s16x8*)(&Qs[(wave * 16 + l16) * ASTR + quad * 8]);
  s16x8 af1 = *(s16x8*)(&Qs[(wave * 16 + l16) * ASTR + 32 + quad * 8]);
  f32x4 oacc[4] = {};
  float mr[4], lr[4];
#pragma unroll
  for (int r = 0; r < 4; ++r) { mr[r] = -1e30f; lr[r] = 0.f; }

  for (int t0 = 0; t0 < SS; t0 += 64) {
    __syncthreads();
    for (int i = tid; i < 512; i += 256) {
      int r = i >> 3, c8 = i & 7;
      *(s16x8*)(&Ks[r * ASTR + c8 * 8]) =
          *(const s16x8*)(k + ((size_t)(t0 + r) * BB + bidx) * KVSTR + hidx * HDIM + c8 * 8);
    }
    for (int i = tid; i < 1024; i += 256) {
      int r = i >> 4, c4 = i & 15;
      s16x4 vv = *(const s16x4*)(v + ((size_t)(t0 + r) * BB + bidx) * KVSTR + hidx * HDIM + c4 * 4);
      Vs[(c4 * 4 + 0) * ASTR + r] = vv.x;
      Vs[(c4 * 4 + 1) * ASTR + r] = vv.y;
      Vs[(c4 * 4 + 2) * ASTR + r] = vv.z;
      Vs[(c4 * 4 + 3) * ASTR + r] = vv.w;
    }
    __syncthreads();
    f32x4 sc[4];
    const f32x4 zero = {};
#pragma unroll
    for (int j = 0; j < 4; ++j) {
      s16x8 kf0 = *(s16x8*)(&Ks[(j * 16 + l16) * ASTR + quad * 8]);
      s16x8 kf1 = *(s16x8*)(&Ks[(j * 16 + l16) * ASTR + 32 + quad * 8]);
      sc[j] = __builtin_amdgcn_mfma_f32_16x16x32_bf16(af0, kf0, zero, 0, 0, 0);
      sc[j] = __builtin_amdgcn_mfma_f32_16x16x32_bf16(af1, kf1, sc[j], 0, 0, 0);
#pragma unroll
      for (int r = 0; r < 4; ++r) sc[j][r] *= 0.125f;
    }
    float tm[4], alpha[4], rs[4];
#pragma unroll
    for (int r = 0; r < 4; ++r) {
      tm[r] = mr[r];
#pragma unroll
      for (int j = 0; j < 4; ++j) tm[r] = fmaxf(tm[r], sc[j][r]);
    }
#pragma unroll
    for (int mask = 1; mask < 16; mask <<= 1)
#pragma unroll
      for (int r = 0; r < 4; ++r) tm[r] = fmaxf(tm[r], __shfl_xor(tm[r], mask));
#pragma unroll
    for (int r = 0; r < 4; ++r) { alpha[r] = __expf(mr[r] - tm[r]); mr[r] = tm[r]; rs[r] = 0.f; }
#pragma unroll
    for (int j = 0; j < 4; ++j)
#pragma unroll
      for (int r = 0; r < 4; ++r) {
        float p = __expf(sc[j][r] - tm[r]);
        sc[j][r] = p; rs[r] += p;
      }
#pragma unroll
    for (int mask = 1; mask < 16; mask <<= 1)
#pragma unroll
      for (int r = 0; r < 4; ++r) rs[r] += __shfl_xor(rs[r], mask);
#pragma unroll
    for (int r = 0; r < 4; ++r) lr[r] = lr[r] * alpha[r] + rs[r];
#pragma unroll
    for (int j = 0; j < 4; ++j)
#pragma unroll
      for (int r = 0; r < 4; ++r)
        Ps[(wave * 16 + quad * 4 + r) * ASTR + j * 16 + l16] = f2bf(sc[j][r]);
#pragma unroll
    for (int jd = 0; jd < 4; ++jd)
#pragma unroll
      for (int r = 0; r < 4; ++r) oacc[jd][r] *= alpha[r];
    __syncthreads();
    s16x8 pf0 = *(s16x8*)(&Ps[(wave * 16 + l16) * ASTR + quad * 8]);
    s16x8 pf1 = *(s16x8*)(&Ps[(wave * 16 + l16) * ASTR + 32 + quad * 8]);
#pragma unroll
    for (int jd = 0; jd < 4; ++jd) {
      s16x8 vf0 = *(s16x8*)(&Vs[(jd * 16 + l16) * ASTR + quad * 8]);
      s16x8 vf1 = *(s16x8*)(&Vs[(jd * 16 + l16) * ASTR + 32 + quad * 8]);
      oacc[jd] = __builtin_amdgcn_mfma_f32_16x16x32_bf16(pf0, vf0, oacc[jd], 0, 0, 0);
      oacc[jd] = __builtin_amdgcn_mfma_f32_16x16x32_bf16(pf1, vf1, oacc[jd], 0, 0, 0);
    }
  }
#pragma unroll
  for (int r = 0; r < 4; ++r) {
    int row = s0 + wave * 16 + quad * 4 + r;
    float invl = 1.f / lr[r];
#pragma unroll
    for (int jd = 0; jd < 4; ++jd) {
      int d = jd * 16 + l16;
      o[((size_t)row * BB + bidx) * DD + hidx * HDIM + d] = f2bf(oacc[jd][r] * invl);
    }
  }
}

// ---------------- expert GEMM 1 (BK=32, 512 threads / 8 thin waves) --------------
// h = gelu(tln[perm] @ w1[e]). Same 128x128 tile + 2-barrier loop as the verified
// round-4 config, but 8 waves each owning a 64x32 sub-tile: acc[4][2] = 32 AGPR
// (vs 64) -> ~95 regs/wave -> 16 waves/CU resident (vs 12). Staging: each wave
// stages 16 A-rows + 16 B-cols per K-step (1 gl2lds each); swizzle unchanged.
__global__ __launch_bounds__(512) void egemm1(const short* __restrict__ tlnbf,
    const short* __restrict__ w1t, const float* __restrict__ b1,
    const int* __restrict__ off, const int* __restrict__ tb, const int* __restrict__ cnt,
    const int* __restrict__ perm, short* __restrict__ hbuf) {
  const int bx = blockIdx.x;
  const int lid = bx >> 3;
  const int rband = lid % 9, colt = lid / 9;
  const int row = (bx & 7) * 9 + rband;
  if (row >= tb[EE]) return;
  int e = 0;
  while (e < EE - 1 && tb[e + 1] <= row) ++e;
  const int lt = row - tb[e];
  const int cnte = cnt[e];
  const int slot0 = off[e] + lt * 128;
  const int slast = off[e] + cnte - 1;
  const int bn = colt * 128;
  const int tid = threadIdx.x;
  const int wave = tid >> 6, lane = tid & 63;            // wave in [0,8)
  const int wr = (wave >> 2) * 64;                       // row half
  const int wc = (wave & 3) * 32;                        // col quarter
  const int l16 = lane & 15, quad = lane >> 4;
  const int kq = (((lane & 3) ^ ((lane >> 3) & 3)) << 3);
  const int sw = ((l16 >> 1) & 3);
  __shared__ short As[128 * 32];
  __shared__ short Bs[128 * 32];
  f32x4 acc[4][2] = {};
  const int sA = slot0 + (wave << 4) + (lane >> 2);      // this lane's A row slot
  const int tokA = perm[sA <= slast ? sA : slast];
  const short* AbA = tlnbf + (size_t)tokA * DD + kq;
  const short* Bb = w1t + (size_t)e * DD * HID
                  + (size_t)(bn + (wave << 4) + (lane >> 2)) * DD + kq;
  short* lA = &As[(wave << 4) * 32];                     // wave's 16-row slice
  short* lB = &Bs[(wave << 4) * 32];
  for (int k0 = 0; k0 < DD; k0 += 32) {
    gl2lds16(AbA + k0, lA);
    gl2lds16(Bb + k0, lB);
    __syncthreads();
    s16x8 af[4], bfr[2];
#pragma unroll
    for (int i = 0; i < 4; ++i)
      af[i] = *(s16x8*)(&As[(wr + i * 16 + l16) * 32 + ((quad ^ sw) << 3)]);
#pragma unroll
    for (int j = 0; j < 2; ++j)
      bfr[j] = *(s16x8*)(&Bs[(wc + j * 16 + l16) * 32 + ((quad ^ sw) << 3)]);
#pragma unroll
    for (int i = 0; i < 4; ++i)
#pragma unroll
      for (int j = 0; j < 2; ++j)
        acc[i][j] = __builtin_amdgcn_mfma_f32_16x16x32_bf16(af[i], bfr[j], acc[i][j], 0, 0, 0);
    __syncthreads();
  }
#pragma unroll
  for (int i = 0; i < 4; ++i) {
#pragma unroll
    for (int r = 0; r < 4; ++r) {
      int rl = wr + i * 16 + quad * 4 + r;
      if (lt * 128 + rl >= cnte) continue;
#pragma unroll
      for (int j = 0; j < 2; ++j) {
        int col = bn + wc + j * 16 + l16;
        float xv = acc[i][j][r] + b1[e * HID + col];
        hbuf[(size_t)(slot0 + rl) * HID + col] = f2bf(gelu_f(xv));
      }
    }
  }
}

// ---------------- expert GEMM 2 (BK=64, 128x64, single-buf) ----------------------
// Best-measured config (round 5): 24.5 KB LDS, K=3072 at 48 barrier steps.
__global__ __launch_bounds__(256) void egemm2(const short* __restrict__ hbuf,
    const short* __restrict__ w2t, const float* __restrict__ b2,
    const int* __restrict__ perm, const int* __restrict__ off,
    const int* __restrict__ tb, const int* __restrict__ cnt,
    const float* __restrict__ gate, const float* __restrict__ x1,
    float* __restrict__ out) {
  const int bx = blockIdx.x;
  const int lid = bx >> 3;
  const int colt = lid % 12, rband = lid / 12;
  const int row = (bx & 7) * 9 + rband;
  if (row >= tb[EE]) return;
  int e = 0;
  while (e < EE - 1 && tb[e + 1] <= row) ++e;
  const int lt = row - tb[e];
  const int cnte = cnt[e];
  const int slot0 = off[e] + lt * 128;
  const int bn = colt * 64;
  const int tid = threadIdx.x;
  const int wave = tid >> 6, lane = tid & 63;
  const int wr = (wave >> 1) * 64, wc = (wave & 1) * 32;
  const int l16 = lane & 15, quad = lane >> 4;
  const int rg = lane >> 3;
  const int kq8 = (((lane & 7) ^ rg) << 3);
  const int swz = l16 & 7;
  __shared__ short As[128 * 64];
  __shared__ short Bs[64 * 64];
  __shared__ int stok[128];
  if (tid < 128) stok[tid] = (lt * 128 + tid < cnte) ? perm[slot0 + tid] : -1;
  f32x4 acc[4][2] = {};
  const short* Ab = hbuf + (size_t)(slot0 + (wave << 5) + rg) * HID + kq8;
  const short* Bb = w2t + (size_t)e * HID * DD
                  + (size_t)(bn + wave * 16 + rg) * HID + kq8;
  short* lA = &As[(wave << 5) * 64];
  short* lB = &Bs[wave * 16 * 64];
  for (int k0 = 0; k0 < HID; k0 += 64) {
    gl2lds16(Ab + k0, lA);
    gl2lds16(Ab + (size_t)8 * HID + k0, lA + 512);
    gl2lds16(Ab + (size_t)16 * HID + k0, lA + 1024);
    gl2lds16(Ab + (size_t)24 * HID + k0, lA + 1536);
    gl2lds16(Bb + k0, lB);
    gl2lds16(Bb + (size_t)8 * HID + k0, lB + 512);
    __syncthreads();
#pragma unroll
    for (int h = 0; h < 2; ++h) {
      s16x8 af[4], bfr[2];
#pragma unroll
      for (int i = 0; i < 4; ++i)
        af[i] = *(s16x8*)(&As[(wr + i * 16 + l16) * 64 + (((quad + 4 * h) ^ swz) << 3)]);
#pragma unroll
      for (int j = 0; j < 2; ++j)
        bfr[j] = *(s16x8*)(&Bs[(wc + j * 16 + l16) * 64 + (((quad + 4 * h) ^ swz) << 3)]);
#pragma unroll
      for (int i = 0; i < 4; ++i)
#pragma unroll
        for (int j = 0; j < 2; ++j)
          acc[i][j] = __builtin_amdgcn_mfma_f32_16x16x32_bf16(af[i], bfr[j], acc[i][j], 0, 0, 0);
    }
    __syncthreads();
  }
#pragma unroll
  for (int i = 0; i < 4; ++i) {
#pragma unroll
    for (int r = 0; r < 4; ++r) {
      int rl = wr + i * 16 + quad * 4 + r;
      if (lt * 128 + rl >= cnte) continue;
      int tok = stok[rl];
      float g = gate[tok];
#pragma unroll
      for (int j = 0; j < 2; ++j) {
        int col = bn + wc + j * 16 + l16;
        float val = acc[i][j][r] + b2[e * DD + col];
        out[(size_t)tok * DD + col] = x1[(size_t)tok * DD + col] + g * val;
      }
    }
  }
}

extern "C" void kernel_launch(void* const* d_in, const int* in_sizes, int n_in,
                              void* d_out, int out_size, void* d_ws, size_t ws_size,
                              hipStream_t stream) {
  const float* x     = (const float*)d_in[0];
  const float* ln1_w = (const float*)d_in[1];
  const float* ln1_b = (const float*)d_in[2];
  const float* wq    = (const float*)d_in[3];
  const float* bq    = (const float*)d_in[4];
  const float* wk    = (const float*)d_in[5];
  const float* bk    = (const float*)d_in[6];
  const float* wv    = (const float*)d_in[7];
  const float* bv    = (const float*)d_in[8];
  const float* wo    = (const float*)d_in[9];
  const float* bo    = (const float*)d_in[10];
  const float* ln2_w = (const float*)d_in[11];
  const float* ln2_b = (const float*)d_in[12];
  const float* wg    = (const float*)d_in[13];
  const float* bg    = (const float*)d_in[14];
  const float* w1    = (const float*)d_in[15];
  const float* b1    = (const float*)d_in[16];
  const float* w2    = (const float*)d_in[17];
  const float* b2    = (const float*)d_in[18];
  float* out = (float*)d_out;
  float* ws = (float*)d_ws;

  const size_t TD = (size_t)TT * DD;
  float* x1    = ws;                 // [TT,DD] fp32 (attn residual out)
  short* tlnbf = (short*)(ws + TD);  // [TT,DD] bf16 (ln2 out, egemm1 A via perm)
  short* sbase = (short*)(ws + 2 * TD);
  short* xbf   = sbase;                         // [TT,DD]
  short* ln1bf = sbase + TD + 128 * DD;         // [TT,DD]; later reused as attbf
  short* attbf = ln1bf;                         // alias (ln1bf dead after QKV)
  short* qbf   = ln1bf + TD;                    // [TT,DD]
  short* kvbf  = qbf + TD;                      // [TT,KVSTR]
  short* hbuf  = kvbf + (size_t)TT * KVSTR;     // [(TT+128),HID]
  short* wqT   = hbuf + (size_t)(TT + 128) * HID;
  short* kvT   = wqT + (size_t)DD * DD;         // contiguous after wqT (kT then vT)
  short* woT   = kvT + (size_t)KVSTR * DD;      // = wqT + 3*DD*DD
  short* w1T   = woT + (size_t)DD * DD;
  short* w2T   = w1T + (size_t)EE * DD * HID;
  int*   meta  = (int*)(w2T + (size_t)EE * HID * DD);
  int*   idx   = meta;
  float* gate  = (float*)(meta + TT);
  int*   perm  = meta + 2 * TT;
  int*   cnt2  = meta + 3 * TT;                 // [NBANK][16] histogram
  int*   cur2  = cnt2 + NBANK * 16;             // [NBANK][16] scatter cursors
  int*   bankbase = cur2 + NBANK * 16;          // [NBANK][EE]
  int*   cnt   = bankbase + NBANK * EE;         // [EE] totals
  int*   off   = cnt + 8;
  int*   tb    = off + 9;
  float* wgT   = (float*)(tb + 9);              // [EE][DD] fp32

  hipMemsetAsync(cnt2, 0, 2 * NBANK * 16 * sizeof(int), stream);

  // weight transposes (fp32 -> bf16 [N,K]); wqT/kT/vT/woT in one launch
  transpose4_bf16<<<dim3(12, 12, 4), 256, 0, stream>>>(wq, wk, wv, wo, wqT);
  transpose_bf16<<<dim3(12, 48, 8), 256, 0, stream>>>(w1, w1T, DD, HID);
  transpose_bf16<<<dim3(48, 12, 8), 256, 0, stream>>>(w2, w2T, HID, DD);
  gate_transpose<<<8, 256, 0, stream>>>(wg, wgT);

  fused_cvt_ln1<<<TT / 4, 256, 0, stream>>>(x, ln1_w, ln1_b, xbf, ln1bf);

  qkv_mgemm<<<8 * 8 * 18, 256, 0, stream>>>(ln1bf, xbf, wqT, kvT, bq, bk, bv, qbf, kvbf);

  attn_mfma<<<dim3(SS / 64, BB, HH), 256, 0, stream>>>(qbf, kvbf, kvbf + DD, attbf);

  mgemm<1, 0, 64><<<64 * 12, 256, 0, stream>>>(attbf, woT, bo, nullptr, x, x1, DD, DD);

  fused_ln2_route<<<TT / 4, 256, 0, stream>>>(x1, ln2_w, ln2_b, wgT, bg,
                                              tlnbf, idx, gate, cnt2);
  prefix2_kernel<<<1, 64, 0, stream>>>(cnt2, cnt, off, tb, bankbase);
  scatter_kernel<<<TT / 256, 256, 0, stream>>>(idx, bankbase, cur2, perm);

  egemm1<<<8 * 9 * 24, 512, 0, stream>>>(tlnbf, w1T, b1, off, tb, cnt, perm, hbuf);
  egemm2<<<8 * 9 * 12, 256, 0, stream>>>(hbuf, w2T, b2, perm, off, tb, cnt, gate, x1, out);
}

// Round 12
// 539.877 us; speedup vs baseline: 1.1112x; 1.0254x over previous
//
#include <hip/hip_runtime.h>
#include <math.h>

#define SS 512
#define BB 16
#define DD 768
#define HH 12
#define HDIM 64
#define EE 8
#define HID 3072
#define TT 8192   // SS*BB tokens
#define EPSV 1e-5f
#define KVSTR 1536
#define ASTR 72   // attention LDS row stride in shorts (144 B, 16B-aligned)
#define NBANK 64  // routing histogram banks

typedef __attribute__((ext_vector_type(8))) short s16x8;
typedef __attribute__((ext_vector_type(4))) short s16x4;
typedef __attribute__((ext_vector_type(4))) float f32x4;

__device__ inline short f2bf(float f) {
  unsigned u = __builtin_bit_cast(unsigned, f);
  unsigned r = (u + 0x7fffu + ((u >> 16) & 1u)) >> 16;
  return (short)r;
}

// tanh-form GELU (max abs err ~3e-4, invisible under bf16 pipeline noise)
__device__ inline float gelu_f(float x) {
  float y = 0.7978845608028654f * (x + 0.044715f * x * x * x);
  float e = __expf(2.f * y);
  float t = 1.f - 2.f / (e + 1.f);
  return 0.5f * x * (1.f + t);
}

// async global->LDS DMA, 16B per lane; LDS dest = wave-uniform base + lane*16
__device__ inline void gl2lds16(const void* g, void* l) {
  __builtin_amdgcn_global_load_lds(
      (const __attribute__((address_space(1))) unsigned int*)g,
      (__attribute__((address_space(3))) unsigned int*)l, 16, 0, 0);
}

// ---------------- 4x DxD transpose + convert in one launch ----------------
__global__ __launch_bounds__(256) void transpose4_bf16(const float* __restrict__ w0,
    const float* __restrict__ w1p, const float* __restrict__ w2p,
    const float* __restrict__ w3p, short* __restrict__ dst) {
  const int z = blockIdx.z;
  const float* W = (z == 0) ? w0 : (z == 1) ? w1p : (z == 2) ? w2p : w3p;
  short* Wt = dst + (size_t)z * DD * DD;
  int k0 = blockIdx.x * 64, n0 = blockIdx.y * 64;
  __shared__ float t[64][65];
  for (int i = threadIdx.x; i < 1024; i += 256) {
    int r = i >> 4, c4 = (i & 15) << 2;
    const float4 v = *(const float4*)(W + (size_t)(k0 + r) * DD + n0 + c4);
    t[r][c4] = v.x; t[r][c4 + 1] = v.y; t[r][c4 + 2] = v.z; t[r][c4 + 3] = v.w;
  }
  __syncthreads();
  for (int i = threadIdx.x; i < 1024; i += 256) {
    int r = i >> 4, c4 = (i & 15) << 2;
    s16x4 sv;
    sv.x = f2bf(t[c4][r]);     sv.y = f2bf(t[c4 + 1][r]);
    sv.z = f2bf(t[c4 + 2][r]); sv.w = f2bf(t[c4 + 3][r]);
    *(s16x4*)(Wt + (size_t)(n0 + r) * DD + k0 + c4) = sv;
  }
}

// ---------------- transpose + convert: W[K,N] fp32 -> Wt[N,K] bf16 ----------------
__global__ __launch_bounds__(256) void transpose_bf16(const float* __restrict__ W,
    short* __restrict__ Wt, int K, int N) {
  const float* Wz = W + (size_t)blockIdx.z * K * N;
  short* Wtz = Wt + (size_t)blockIdx.z * K * N;
  int k0 = blockIdx.x * 64, n0 = blockIdx.y * 64;
  __shared__ float t[64][65];
  for (int i = threadIdx.x; i < 1024; i += 256) {
    int r = i >> 4, c4 = (i & 15) << 2;
    const float4 v = *(const float4*)(Wz + (size_t)(k0 + r) * N + n0 + c4);
    t[r][c4] = v.x; t[r][c4 + 1] = v.y; t[r][c4 + 2] = v.z; t[r][c4 + 3] = v.w;
  }
  __syncthreads();
  for (int i = threadIdx.x; i < 1024; i += 256) {
    int r = i >> 4, c4 = (i & 15) << 2;
    s16x4 sv;
    sv.x = f2bf(t[c4][r]);     sv.y = f2bf(t[c4 + 1][r]);
    sv.z = f2bf(t[c4 + 2][r]); sv.w = f2bf(t[c4 + 3][r]);
    *(s16x4*)(Wtz + (size_t)(n0 + r) * K + k0 + c4) = sv;
  }
}

// ---------------- gating weight transpose: wg[D,E] fp32 -> wgT[E,D] fp32 ----------
__global__ __launch_bounds__(256) void gate_transpose(const float* __restrict__ wg,
    float* __restrict__ wgT) {
  for (int i = threadIdx.x + blockIdx.x * 256; i < EE * DD; i += 256 * 8) {
    int e = i / DD, d = i - e * DD;
    wgT[i] = wg[d * EE + e];
  }
}

// ---------------- fused x->bf16 convert + LayerNorm1 (wave-per-token) ----------------
__global__ __launch_bounds__(256) void fused_cvt_ln1(const float* __restrict__ x,
    const float* __restrict__ w, const float* __restrict__ b,
    short* __restrict__ xbf, short* __restrict__ ln1bf) {
  const int tok = blockIdx.x * 4 + (threadIdx.x >> 6);
  const int lane = threadIdx.x & 63;
  const float* row = x + (size_t)tok * DD;
  const float4 v0 = *(const float4*)(row + lane * 4);
  const float4 v1 = *(const float4*)(row + 256 + lane * 4);
  const float4 v2 = *(const float4*)(row + 512 + lane * 4);
  float s = v0.x + v0.y + v0.z + v0.w + v1.x + v1.y + v1.z + v1.w
          + v2.x + v2.y + v2.z + v2.w;
  float ss = v0.x * v0.x + v0.y * v0.y + v0.z * v0.z + v0.w * v0.w
           + v1.x * v1.x + v1.y * v1.y + v1.z * v1.z + v1.w * v1.w
           + v2.x * v2.x + v2.y * v2.y + v2.z * v2.z + v2.w * v2.w;
#pragma unroll
  for (int o = 1; o < 64; o <<= 1) { s += __shfl_xor(s, o); ss += __shfl_xor(ss, o); }
  const float mean = s * (1.f / DD);
  const float inv = rsqrtf(ss * (1.f / DD) - mean * mean + EPSV);
  short* xrow = xbf + (size_t)tok * DD;
  short* lrow = ln1bf + (size_t)tok * DD;
#define LN1_CHUNK(v, off) { \
  const float4 wv = *(const float4*)(w + (off) + lane * 4); \
  const float4 bv = *(const float4*)(b + (off) + lane * 4); \
  s16x4 xa, la; \
  xa.x = f2bf(v.x); xa.y = f2bf(v.y); xa.z = f2bf(v.z); xa.w = f2bf(v.w); \
  la.x = f2bf((v.x - mean) * inv * wv.x + bv.x); \
  la.y = f2bf((v.y - mean) * inv * wv.y + bv.y); \
  la.z = f2bf((v.z - mean) * inv * wv.z + bv.z); \
  la.w = f2bf((v.w - mean) * inv * wv.w + bv.w); \
  *(s16x4*)(xrow + (off) + lane * 4) = xa; \
  *(s16x4*)(lrow + (off) + lane * 4) = la; }
  LN1_CHUNK(v0, 0)
  LN1_CHUNK(v1, 256)
  LN1_CHUNK(v2, 512)
#undef LN1_CHUNK
}

// ---------------- fused LayerNorm2 + MoE routing (wave-per-token) ----------------
__global__ __launch_bounds__(256) void fused_ln2_route(const float* __restrict__ x1,
    const float* __restrict__ w, const float* __restrict__ b,
    const float* __restrict__ wgT, const float* __restrict__ bg,
    short* __restrict__ tlnbf, int* __restrict__ idx, float* __restrict__ gate,
    int* __restrict__ cnt2) {
  const int tok = blockIdx.x * 4 + (threadIdx.x >> 6);
  const int lane = threadIdx.x & 63;
  const float* row = x1 + (size_t)tok * DD;
  const float4 v0 = *(const float4*)(row + lane * 4);
  const float4 v1 = *(const float4*)(row + 256 + lane * 4);
  const float4 v2 = *(const float4*)(row + 512 + lane * 4);
  float s = v0.x + v0.y + v0.z + v0.w + v1.x + v1.y + v1.z + v1.w
          + v2.x + v2.y + v2.z + v2.w;
  float ss = v0.x * v0.x + v0.y * v0.y + v0.z * v0.z + v0.w * v0.w
           + v1.x * v1.x + v1.y * v1.y + v1.z * v1.z + v1.w * v1.w
           + v2.x * v2.x + v2.y * v2.y + v2.z * v2.z + v2.w * v2.w;
#pragma unroll
  for (int o = 1; o < 64; o <<= 1) { s += __shfl_xor(s, o); ss += __shfl_xor(ss, o); }
  const float mean = s * (1.f / DD);
  const float inv = rsqrtf(ss * (1.f / DD) - mean * mean + EPSV);
  short* srow = tlnbf + (size_t)tok * DD;
  float acc[EE];
#pragma unroll
  for (int e = 0; e < EE; ++e) acc[e] = 0.f;
#define LN2_CHUNK(v, off) { \
  const float4 wv = *(const float4*)(w + (off) + lane * 4); \
  const float4 bv = *(const float4*)(b + (off) + lane * 4); \
  float4 n; \
  n.x = (v.x - mean) * inv * wv.x + bv.x; \
  n.y = (v.y - mean) * inv * wv.y + bv.y; \
  n.z = (v.z - mean) * inv * wv.z + bv.z; \
  n.w = (v.w - mean) * inv * wv.w + bv.w; \
  s16x4 sv; sv.x = f2bf(n.x); sv.y = f2bf(n.y); sv.z = f2bf(n.z); sv.w = f2bf(n.w); \
  *(s16x4*)(srow + (off) + lane * 4) = sv; \
  const int i0 = (off) + lane * 4; \
  _Pragma("unroll") \
  for (int e = 0; e < EE; ++e) { \
    const float4 g = *(const float4*)(wgT + (size_t)e * DD + i0); \
    acc[e] += n.x * g.x + n.y * g.y + n.z * g.z + n.w * g.w; } }
  LN2_CHUNK(v0, 0)
  LN2_CHUNK(v1, 256)
  LN2_CHUNK(v2, 512)
#undef LN2_CHUNK
#pragma unroll
  for (int o = 1; o < 64; o <<= 1)
#pragma unroll
    for (int e = 0; e < EE; ++e) acc[e] += __shfl_xor(acc[e], o);
  if (lane == 0) {
#pragma unroll
    for (int e = 0; e < EE; ++e) acc[e] += bg[e];
    int best = 0; float bm = acc[0];
#pragma unroll
    for (int e = 1; e < EE; ++e) if (acc[e] > bm) { bm = acc[e]; best = e; }
    float sum = 0.f;
#pragma unroll
    for (int e = 0; e < EE; ++e) sum += __expf(acc[e] - bm);
    idx[tok] = best;
    gate[tok] = 1.0f / sum;
    atomicAdd(&cnt2[(blockIdx.x & (NBANK - 1)) * 16 + best], 1);
  }
}

// ---------------- prefix over banked histogram (1 wave) ----------------
__global__ void prefix2_kernel(const int* __restrict__ cnt2, int* __restrict__ cnt,
                               int* __restrict__ off, int* __restrict__ tb,
                               int* __restrict__ bankbase) {
  const int lane = threadIdx.x;   // 64 threads, 1 wave
  int c[EE], excl[EE], tot[EE];
#pragma unroll
  for (int e = 0; e < EE; ++e) c[e] = cnt2[lane * 16 + e];
#pragma unroll
  for (int e = 0; e < EE; ++e) {
    int x = c[e];
#pragma unroll
    for (int o = 1; o < 64; o <<= 1) {
      int y = __shfl_up(x, o);
      if (lane >= o) x += y;
    }
    excl[e] = x - c[e];
    tot[e] = __shfl(x, 63);
  }
  int oo = 0;
  int offl[EE];
#pragma unroll
  for (int e = 0; e < EE; ++e) { offl[e] = oo; oo += tot[e]; }
#pragma unroll
  for (int e = 0; e < EE; ++e)
    bankbase[lane * EE + e] = offl[e] + excl[e];
  if (lane == 0) {
    int o = 0, t = 0;
    for (int e = 0; e < EE; ++e) {
      off[e] = o; tb[e] = t; cnt[e] = tot[e];
      o += tot[e]; t += (tot[e] + 127) >> 7;
    }
    off[EE] = o; tb[EE] = t;
  }
}

// ---------------- scatter via banked cursors (low-contention atomics) ----------
__global__ __launch_bounds__(256) void scatter_kernel(const int* __restrict__ idx,
    const int* __restrict__ bankbase, int* __restrict__ cur2, int* __restrict__ perm) {
  int t = blockIdx.x * 256 + threadIdx.x;
  if (t < TT) {
    int e = idx[t];
    int bank = (t >> 2) & (NBANK - 1);
    int p = atomicAdd(&cur2[bank * 16 + e], 1);
    perm[bankbase[bank * EE + e] + p] = t;
  }
}

// ---------------- bf16 MFMA GEMM, DMA staging + XOR-swizzled LDS (BK=32) --------
template<int MODE, int OUTBF, int COLS>
__global__ __launch_bounds__(256) void mgemm(const short* __restrict__ A,
    const short* __restrict__ Wt, const float* __restrict__ bias,
    const float* __restrict__ bias2, const float* __restrict__ res,
    void* __restrict__ C, int N, int K) {
  const int bx = blockIdx.x;
  const int lid = bx >> 3;
  const int colt = lid >> 3, rband = lid & 7;
  const int bm = (((bx & 7) << 3) + rband) * 128;
  const int bn = colt * COLS;
  constexpr int NJ = COLS / 32;
  __shared__ short As[128 * 32];
  __shared__ short Bs[COLS * 32];
  const int tid = threadIdx.x;
  const int wave = tid >> 6, lane = tid & 63;
  const int wr = (wave >> 1) * 64, wc = (wave & 1) * (COLS / 2);
  const int l16 = lane & 15, quad = lane >> 4;
  const int kq = (((lane & 3) ^ ((lane >> 3) & 3)) << 3);
  const int sw = ((l16 >> 1) & 3);
  const short* Ab = A + (size_t)(bm + (wave << 5) + (lane >> 2)) * K + kq;
  const short* Bb = Wt + (size_t)(bn + wave * (COLS / 4) + (lane >> 2)) * K + kq;
  short* lA = &As[(wave << 5) * 32];
  short* lB = &Bs[wave * (COLS / 4) * 32];
  f32x4 acc[4][NJ] = {};
  for (int k0 = 0; k0 < K; k0 += 32) {
    gl2lds16(Ab + k0, lA);
    gl2lds16(Ab + (size_t)16 * K + k0, lA + 512);
    gl2lds16(Bb + k0, lB);
    if (COLS == 128) gl2lds16(Bb + (size_t)16 * K + k0, lB + 512);
    __syncthreads();
    s16x8 af[4], bfr[NJ];
#pragma unroll
    for (int i = 0; i < 4; ++i)
      af[i] = *(s16x8*)(&As[(wr + i * 16 + l16) * 32 + ((quad ^ sw) << 3)]);
#pragma unroll
    for (int j = 0; j < NJ; ++j)
      bfr[j] = *(s16x8*)(&Bs[(wc + j * 16 + l16) * 32 + ((quad ^ sw) << 3)]);
#pragma unroll
    for (int i = 0; i < 4; ++i)
#pragma unroll
      for (int j = 0; j < NJ; ++j)
        acc[i][j] = __builtin_amdgcn_mfma_f32_16x16x32_bf16(af[i], bfr[j], acc[i][j], 0, 0, 0);
    __syncthreads();
  }
#pragma unroll
  for (int i = 0; i < 4; ++i) {
#pragma unroll
    for (int r = 0; r < 4; ++r) {
      int row = bm + wr + i * 16 + quad * 4 + r;
#pragma unroll
      for (int j = 0; j < NJ; ++j) {
        int col = bn + wc + j * 16 + l16;
        float bv = (MODE == 2) ? (col >= DD ? bias2[col - DD] : bias[col]) : bias[col];
        float val = acc[i][j][r] + bv;
        if (MODE == 1) val += res[(size_t)row * N + col];
        if (OUTBF) ((short*)C)[(size_t)row * N + col] = f2bf(val);
        else       ((float*)C)[(size_t)row * N + col] = val;
      }
    }
  }
}

// ---------------- merged Q-proj + KV-proj (BK=64, 512 threads / 8 thin waves) -----
// colt<6: Q = ln1bf @ wqT ; colt>=6: KV = xbf @ kvT. 12 K-steps, 16 MFMA per
// wave per barrier pair (egemm2's proven BK=64 swizzle: kq8/swz, row&7-periodic).
__global__ __launch_bounds__(512) void qkv_mgemm(const short* __restrict__ ln1bf,
    const short* __restrict__ xbf, const short* __restrict__ wqT,
    const short* __restrict__ kvT, const float* __restrict__ bq,
    const float* __restrict__ bk, const float* __restrict__ bv,
    short* __restrict__ qbf, short* __restrict__ kvbf) {
  const int bx = blockIdx.x;
  const int lid = bx >> 3;
  const int colt = lid >> 3, rband = lid & 7;   // colt in [0,18)
  const int bm = (((bx & 7) << 3) + rband) * 128;
  const bool isQ = (colt < 6);
  const int bn = isQ ? colt * 128 : (colt - 6) * 128;
  const short* A  = isQ ? ln1bf : xbf;
  const short* Bt = isQ ? wqT : kvT;
  const float* bias = isQ ? bq : (bn < DD ? bk : bv);
  const int bofs = (!isQ && bn >= DD) ? DD : 0;
  short* out = isQ ? qbf : kvbf;
  const int OS = isQ ? DD : KVSTR;
  const int K = DD;
  __shared__ short As[128 * 64];
  __shared__ short Bs[128 * 64];
  const int tid = threadIdx.x;
  const int wave = tid >> 6, lane = tid & 63;   // 8 waves
  const int wr = (wave >> 2) * 64;              // row half
  const int wc = (wave & 3) * 32;               // col quarter
  const int l16 = lane & 15, quad = lane >> 4;
  const int rg = lane >> 3;
  const int kq8 = (((lane & 7) ^ rg) << 3);
  const int swz = l16 & 7;
  const short* Ab = A + (size_t)(bm + (wave << 4) + rg) * K + kq8;
  const short* Bb = Bt + (size_t)(bn + (wave << 4) + rg) * K + kq8;
  short* lA = &As[(wave << 4) * 64];
  short* lB = &Bs[(wave << 4) * 64];
  f32x4 acc[4][2] = {};
  for (int k0 = 0; k0 < K; k0 += 64) {
    gl2lds16(Ab + k0, lA);
    gl2lds16(Ab + (size_t)8 * K + k0, lA + 512);
    gl2lds16(Bb + k0, lB);
    gl2lds16(Bb + (size_t)8 * K + k0, lB + 512);
    __syncthreads();
#pragma unroll
    for (int h = 0; h < 2; ++h) {
      s16x8 af[4], bfr[2];
#pragma unroll
      for (int i = 0; i < 4; ++i)
        af[i] = *(s16x8*)(&As[(wr + i * 16 + l16) * 64 + (((quad + 4 * h) ^ swz) << 3)]);
#pragma unroll
      for (int j = 0; j < 2; ++j)
        bfr[j] = *(s16x8*)(&Bs[(wc + j * 16 + l16) * 64 + (((quad + 4 * h) ^ swz) << 3)]);
#pragma unroll
      for (int i = 0; i < 4; ++i)
#pragma unroll
        for (int j = 0; j < 2; ++j)
          acc[i][j] = __builtin_amdgcn_mfma_f32_16x16x32_bf16(af[i], bfr[j], acc[i][j], 0, 0, 0);
    }
    __syncthreads();
  }
#pragma unroll
  for (int i = 0; i < 4; ++i) {
#pragma unroll
    for (int r = 0; r < 4; ++r) {
      int row = bm + wr + i * 16 + quad * 4 + r;
#pragma unroll
      for (int j = 0; j < 2; ++j) {
        int col = bn + wc + j * 16 + l16;
        float val = acc[i][j][r] + bias[col - bofs];
        out[(size_t)row * OS + col] = f2bf(val);
      }
    }
  }
}

// ---------------- flash attention, bf16 MFMA, bf16 IO ----------------
__global__ __launch_bounds__(256) void attn_mfma(const short* __restrict__ q,
    const short* __restrict__ k, const short* __restrict__ v, short* __restrict__ o) {
  const int qt = blockIdx.x, bidx = blockIdx.y, hidx = blockIdx.z;
  const int tid = threadIdx.x;
  const int wave = tid >> 6, lane = tid & 63;
  const int l16 = lane & 15, quad = lane >> 4;
  const int s0 = qt * 64;
  __shared__ short Qs[64 * ASTR];
  __shared__ short Ks[64 * ASTR];
  __shared__ short Vs[64 * ASTR];   // transposed: Vs[d][key]
  __shared__ short Ps[64 * ASTR];
  for (int i = tid; i < 512; i += 256) {
    int r = i >> 3, c8 = i & 7;
    *(s16x8*)(&Qs[r * ASTR + c8 * 8]) =
        *(const s16x8*)(q + ((size_t)(s0 + r) * BB + bidx) * DD + hidx * HDIM + c8 * 8);
  }
  __syncthreads();
  s16x8 af0 = *(s16x8*)(&Qs[(wave * 16 + l16) * ASTR + quad * 8]);
  s16x8 af1 = *(s16x8*)(&Qs[(wave * 16 + l16) * ASTR + 32 + quad * 8]);
  f32x4 oacc[4] = {};
  float mr[4], lr[4];
#pragma unroll
  for (int r = 0; r < 4; ++r) { mr[r] = -1e30f; lr[r] = 0.f; }

  for (int t0 = 0; t0 < SS; t0 += 64) {
    __syncthreads();
    for (int i = tid; i < 512; i += 256) {
      int r = i >> 3, c8 = i & 7;
      *(s16x8*)(&Ks[r * ASTR + c8 * 8]) =
          *(const s16x8*)(k + ((size_t)(t0 + r) * BB + bidx) * KVSTR + hidx * HDIM + c8 * 8);
    }
    for (int i = tid; i < 1024; i += 256) {
      int r = i >> 4, c4 = i & 15;
      s16x4 vv = *(const s16x4*)(v + ((size_t)(t0 + r) * BB + bidx) * KVSTR + hidx * HDIM + c4 * 4);
      Vs[(c4 * 4 + 0) * ASTR + r] = vv.x;
      Vs[(c4 * 4 + 1) * ASTR + r] = vv.y;
      Vs[(c4 * 4 + 2) * ASTR + r] = vv.z;
      Vs[(c4 * 4 + 3) * ASTR + r] = vv.w;
    }
    __syncthreads();
    f32x4 sc[4];
    const f32x4 zero = {};
#pragma unroll
    for (int j = 0; j < 4; ++j) {
      s16x8 kf0 = *(s16x8*)(&Ks[(j * 16 + l16) * ASTR + quad * 8]);
      s16x8 kf1 = *(s16x8*)(&Ks[(j * 16 + l16) * ASTR + 32 + quad * 8]);
      sc[j] = __builtin_amdgcn_mfma_f32_16x16x32_bf16(af0, kf0, zero, 0, 0, 0);
      sc[j] = __builtin_amdgcn_mfma_f32_16x16x32_bf16(af1, kf1, sc[j], 0, 0, 0);
#pragma unroll
      for (int r = 0; r < 4; ++r) sc[j][r] *= 0.125f;
    }
    float tm[4], alpha[4], rs[4];
#pragma unroll
    for (int r = 0; r < 4; ++r) {
      tm[r] = mr[r];
#pragma unroll
      for (int j = 0; j < 4; ++j) tm[r] = fmaxf(tm[r], sc[j][r]);
    }
#pragma unroll
    for (int mask = 1; mask < 16; mask <<= 1)
#pragma unroll
      for (int r = 0; r < 4; ++r) tm[r] = fmaxf(tm[r], __shfl_xor(tm[r], mask));
#pragma unroll
    for (int r = 0; r < 4; ++r) { alpha[r] = __expf(mr[r] - tm[r]); mr[r] = tm[r]; rs[r] = 0.f; }
#pragma unroll
    for (int j = 0; j < 4; ++j)
#pragma unroll
      for (int r = 0; r < 4; ++r) {
        float p = __expf(sc[j][r] - tm[r]);
        sc[j][r] = p; rs[r] += p;
      }
#pragma unroll
    for (int mask = 1; mask < 16; mask <<= 1)
#pragma unroll
      for (int r = 0; r < 4; ++r) rs[r] += __shfl_xor(rs[r], mask);
#pragma unroll
    for (int r = 0; r < 4; ++r) lr[r] = lr[r] * alpha[r] + rs[r];
#pragma unroll
    for (int j = 0; j < 4; ++j)
#pragma unroll
      for (int r = 0; r < 4; ++r)
        Ps[(wave * 16 + quad * 4 + r) * ASTR + j * 16 + l16] = f2bf(sc[j][r]);
#pragma unroll
    for (int jd = 0; jd < 4; ++jd)
#pragma unroll
      for (int r = 0; r < 4; ++r) oacc[jd][r] *= alpha[r];
    __syncthreads();
    s16x8 pf0 = *(s16x8*)(&Ps[(wave * 16 + l16) * ASTR + quad * 8]);
    s16x8 pf1 = *(s16x8*)(&Ps[(wave * 16 + l16) * ASTR + 32 + quad * 8]);
#pragma unroll
    for (int jd = 0; jd < 4; ++jd) {
      s16x8 vf0 = *(s16x8*)(&Vs[(jd * 16 + l16) * ASTR + quad * 8]);
      s16x8 vf1 = *(s16x8*)(&Vs[(jd * 16 + l16) * ASTR + 32 + quad * 8]);
      oacc[jd] = __builtin_amdgcn_mfma_f32_16x16x32_bf16(pf0, vf0, oacc[jd], 0, 0, 0);
      oacc[jd] = __builtin_amdgcn_mfma_f32_16x16x32_bf16(pf1, vf1, oacc[jd], 0, 0, 0);
    }
  }
#pragma unroll
  for (int r = 0; r < 4; ++r) {
    int row = s0 + wave * 16 + quad * 4 + r;
    float invl = 1.f / lr[r];
#pragma unroll
    for (int jd = 0; jd < 4; ++jd) {
      int d = jd * 16 + l16;
      o[((size_t)row * BB + bidx) * DD + hidx * HDIM + d] = f2bf(oacc[jd][r] * invl);
    }
  }
}

// ---------------- expert GEMM 1 (BK=64, 512 threads / 8 thin waves) --------------
// h = gelu(tln[perm] @ w1[e]). 12 K-steps (vs 24), 16 MFMA per wave per barrier
// pair; A rows gathered via perm (two lookups: +rg, +rg+8), egemm2 BK=64 swizzle.
__global__ __launch_bounds__(512) void egemm1(const short* __restrict__ tlnbf,
    const short* __restrict__ w1t, const float* __restrict__ b1,
    const int* __restrict__ off, const int* __restrict__ tb, const int* __restrict__ cnt,
    const int* __restrict__ perm, short* __restrict__ hbuf) {
  const int bx = blockIdx.x;
  const int lid = bx >> 3;
  const int rband = lid % 9, colt = lid / 9;
  const int row = (bx & 7) * 9 + rband;
  if (row >= tb[EE]) return;
  int e = 0;
  while (e < EE - 1 && tb[e + 1] <= row) ++e;
  const int lt = row - tb[e];
  const int cnte = cnt[e];
  const int slot0 = off[e] + lt * 128;
  const int slast = off[e] + cnte - 1;
  const int bn = colt * 128;
  const int tid = threadIdx.x;
  const int wave = tid >> 6, lane = tid & 63;   // 8 waves
  const int wr = (wave >> 2) * 64;
  const int wc = (wave & 3) * 32;
  const int l16 = lane & 15, quad = lane >> 4;
  const int rg = lane >> 3;
  const int kq8 = (((lane & 7) ^ rg) << 3);
  const int swz = l16 & 7;
  __shared__ short As[128 * 64];
  __shared__ short Bs[128 * 64];
  f32x4 acc[4][2] = {};
  const int sA0 = slot0 + (wave << 4) + rg;
  const int tokA = perm[sA0 <= slast ? sA0 : slast];
  const int tokB = perm[(sA0 + 8) <= slast ? (sA0 + 8) : slast];
  const short* AbA = tlnbf + (size_t)tokA * DD + kq8;
  const short* AbB = tlnbf + (size_t)tokB * DD + kq8;
  const short* Bb = w1t + (size_t)e * DD * HID
                  + (size_t)(bn + (wave << 4) + rg) * DD + kq8;
  short* lA = &As[(wave << 4) * 64];
  short* lB = &Bs[(wave << 4) * 64];
  for (int k0 = 0; k0 < DD; k0 += 64) {
    gl2lds16(AbA + k0, lA);
    gl2lds16(AbB + k0, lA + 512);
    gl2lds16(Bb + k0, lB);
    gl2lds16(Bb + (size_t)8 * DD + k0, lB + 512);
    __syncthreads();
#pragma unroll
    for (int h = 0; h < 2; ++h) {
      s16x8 af[4], bfr[2];
#pragma unroll
      for (int i = 0; i < 4; ++i)
        af[i] = *(s16x8*)(&As[(wr + i * 16 + l16) * 64 + (((quad + 4 * h) ^ swz) << 3)]);
#pragma unroll
      for (int j = 0; j < 2; ++j)
        bfr[j] = *(s16x8*)(&Bs[(wc + j * 16 + l16) * 64 + (((quad + 4 * h) ^ swz) << 3)]);
#pragma unroll
      for (int i = 0; i < 4; ++i)
#pragma unroll
        for (int j = 0; j < 2; ++j)
          acc[i][j] = __builtin_amdgcn_mfma_f32_16x16x32_bf16(af[i], bfr[j], acc[i][j], 0, 0, 0);
    }
    __syncthreads();
  }
#pragma unroll
  for (int i = 0; i < 4; ++i) {
#pragma unroll
    for (int r = 0; r < 4; ++r) {
      int rl = wr + i * 16 + quad * 4 + r;
      if (lt * 128 + rl >= cnte) continue;
#pragma unroll
      for (int j = 0; j < 2; ++j) {
        int col = bn + wc + j * 16 + l16;
        float xv = acc[i][j][r] + b1[e * HID + col];
        hbuf[(size_t)(slot0 + rl) * HID + col] = f2bf(gelu_f(xv));
      }
    }
  }
}

// ---------------- expert GEMM 2 (BK=64, 128x64, single-buf) ----------------------
// Best-measured config (round 5): 24.5 KB LDS, K=3072 at 48 barrier steps.
__global__ __launch_bounds__(256) void egemm2(const short* __restrict__ hbuf,
    const short* __restrict__ w2t, const float* __restrict__ b2,
    const int* __restrict__ perm, const int* __restrict__ off,
    const int* __restrict__ tb, const int* __restrict__ cnt,
    const float* __restrict__ gate, const float* __restrict__ x1,
    float* __restrict__ out) {
  const int bx = blockIdx.x;
  const int lid = bx >> 3;
  const int colt = lid % 12, rband = lid / 12;
  const int row = (bx & 7) * 9 + rband;
  if (row >= tb[EE]) return;
  int e = 0;
  while (e < EE - 1 && tb[e + 1] <= row) ++e;
  const int lt = row - tb[e];
  const int cnte = cnt[e];
  const int slot0 = off[e] + lt * 128;
  const int bn = colt * 64;
  const int tid = threadIdx.x;
  const int wave = tid >> 6, lane = tid & 63;
  const int wr = (wave >> 1) * 64, wc = (wave & 1) * 32;
  const int l16 = lane & 15, quad = lane >> 4;
  const int rg = lane >> 3;
  const int kq8 = (((lane & 7) ^ rg) << 3);
  const int swz = l16 & 7;
  __shared__ short As[128 * 64];
  __shared__ short Bs[64 * 64];
  __shared__ int stok[128];
  if (tid < 128) stok[tid] = (lt * 128 + tid < cnte) ? perm[slot0 + tid] : -1;
  f32x4 acc[4][2] = {};
  const short* Ab = hbuf + (size_t)(slot0 + (wave << 5) + rg) * HID + kq8;
  const short* Bb = w2t + (size_t)e * HID * DD
                  + (size_t)(bn + wave * 16 + rg) * HID + kq8;
  short* lA = &As[(wave << 5) * 64];
  short* lB = &Bs[wave * 16 * 64];
  for (int k0 = 0; k0 < HID; k0 += 64) {
    gl2lds16(Ab + k0, lA);
    gl2lds16(Ab + (size_t)8 * HID + k0, lA + 512);
    gl2lds16(Ab + (size_t)16 * HID + k0, lA + 1024);
    gl2lds16(Ab + (size_t)24 * HID + k0, lA + 1536);
    gl2lds16(Bb + k0, lB);
    gl2lds16(Bb + (size_t)8 * HID + k0, lB + 512);
    __syncthreads();
#pragma unroll
    for (int h = 0; h < 2; ++h) {
      s16x8 af[4], bfr[2];
#pragma unroll
      for (int i = 0; i < 4; ++i)
        af[i] = *(s16x8*)(&As[(wr + i * 16 + l16) * 64 + (((quad + 4 * h) ^ swz) << 3)]);
#pragma unroll
      for (int j = 0; j < 2; ++j)
        bfr[j] = *(s16x8*)(&Bs[(wc + j * 16 + l16) * 64 + (((quad + 4 * h) ^ swz) << 3)]);
#pragma unroll
      for (int i = 0; i < 4; ++i)
#pragma unroll
        for (int j = 0; j < 2; ++j)
          acc[i][j] = __builtin_amdgcn_mfma_f32_16x16x32_bf16(af[i], bfr[j], acc[i][j], 0, 0, 0);
    }
    __syncthreads();
  }
#pragma unroll
  for (int i = 0; i < 4; ++i) {
#pragma unroll
    for (int r = 0; r < 4; ++r) {
      int rl = wr + i * 16 + quad * 4 + r;
      if (lt * 128 + rl >= cnte) continue;
      int tok = stok[rl];
      float g = gate[tok];
#pragma unroll
      for (int j = 0; j < 2; ++j) {
        int col = bn + wc + j * 16 + l16;
        float val = acc[i][j][r] + b2[e * DD + col];
        out[(size_t)tok * DD + col] = x1[(size_t)tok * DD + col] + g * val;
      }
    }
  }
}

extern "C" void kernel_launch(void* const* d_in, const int* in_sizes, int n_in,
                              void* d_out, int out_size, void* d_ws, size_t ws_size,
                              hipStream_t stream) {
  const float* x     = (const float*)d_in[0];
  const float* ln1_w = (const float*)d_in[1];
  const float* ln1_b = (const float*)d_in[2];
  const float* wq    = (const float*)d_in[3];
  const float* bq    = (const float*)d_in[4];
  const float* wk    = (const float*)d_in[5];
  const float* bk    = (const float*)d_in[6];
  const float* wv    = (const float*)d_in[7];
  const float* bv    = (const float*)d_in[8];
  const float* wo    = (const float*)d_in[9];
  const float* bo    = (const float*)d_in[10];
  const float* ln2_w = (const float*)d_in[11];
  const float* ln2_b = (const float*)d_in[12];
  const float* wg    = (const float*)d_in[13];
  const float* bg    = (const float*)d_in[14];
  const float* w1    = (const float*)d_in[15];
  const float* b1    = (const float*)d_in[16];
  const float* w2    = (const float*)d_in[17];
  const float* b2    = (const float*)d_in[18];
  float* out = (float*)d_out;
  float* ws = (float*)d_ws;

  const size_t TD = (size_t)TT * DD;
  float* x1    = ws;                 // [TT,DD] fp32 (attn residual out)
  short* tlnbf = (short*)(ws + TD);  // [TT,DD] bf16 (ln2 out, egemm1 A via perm)
  short* sbase = (short*)(ws + 2 * TD);
  short* xbf   = sbase;                         // [TT,DD]
  short* ln1bf = sbase + TD + 128 * DD;         // [TT,DD]; later reused as attbf
  short* attbf = ln1bf;                         // alias (ln1bf dead after QKV)
  short* qbf   = ln1bf + TD;                    // [TT,DD]
  short* kvbf  = qbf + TD;                      // [TT,KVSTR]
  short* hbuf  = kvbf + (size_t)TT * KVSTR;     // [(TT+128),HID]
  short* wqT   = hbuf + (size_t)(TT + 128) * HID;
  short* kvT   = wqT + (size_t)DD * DD;         // contiguous after wqT (kT then vT)
  short* woT   = kvT + (size_t)KVSTR * DD;      // = wqT + 3*DD*DD
  short* w1T   = woT + (size_t)DD * DD;
  short* w2T   = w1T + (size_t)EE * DD * HID;
  int*   meta  = (int*)(w2T + (size_t)EE * HID * DD);
  int*   idx   = meta;
  float* gate  = (float*)(meta + TT);
  int*   perm  = meta + 2 * TT;
  int*   cnt2  = meta + 3 * TT;                 // [NBANK][16] histogram
  int*   cur2  = cnt2 + NBANK * 16;             // [NBANK][16] scatter cursors
  int*   bankbase = cur2 + NBANK * 16;          // [NBANK][EE]
  int*   cnt   = bankbase + NBANK * EE;         // [EE] totals
  int*   off   = cnt + 8;
  int*   tb    = off + 9;
  float* wgT   = (float*)(tb + 9);              // [EE][DD] fp32

  hipMemsetAsync(cnt2, 0, 2 * NBANK * 16 * sizeof(int), stream);

  // weight transposes (fp32 -> bf16 [N,K]); wqT/kT/vT/woT in one launch
  transpose4_bf16<<<dim3(12, 12, 4), 256, 0, stream>>>(wq, wk, wv, wo, wqT);
  transpose_bf16<<<dim3(12, 48, 8), 256, 0, stream>>>(w1, w1T, DD, HID);
  transpose_bf16<<<dim3(48, 12, 8), 256, 0, stream>>>(w2, w2T, HID, DD);
  gate_transpose<<<8, 256, 0, stream>>>(wg, wgT);

  fused_cvt_ln1<<<TT / 4, 256, 0, stream>>>(x, ln1_w, ln1_b, xbf, ln1bf);

  qkv_mgemm<<<8 * 8 * 18, 512, 0, stream>>>(ln1bf, xbf, wqT, kvT, bq, bk, bv, qbf, kvbf);

  attn_mfma<<<dim3(SS / 64, BB, HH), 256, 0, stream>>>(qbf, kvbf, kvbf + DD, attbf);

  mgemm<1, 0, 64><<<64 * 12, 256, 0, stream>>>(attbf, woT, bo, nullptr, x, x1, DD, DD);

  fused_ln2_route<<<TT / 4, 256, 0, stream>>>(x1, ln2_w, ln2_b, wgT, bg,
                                              tlnbf, idx, gate, cnt2);
  prefix2_kernel<<<1, 64, 0, stream>>>(cnt2, cnt, off, tb, bankbase);
  scatter_kernel<<<TT / 256, 256, 0, stream>>>(idx, bankbase, cur2, perm);

  egemm1<<<8 * 9 * 24, 512, 0, stream>>>(tlnbf, w1T, b1, off, tb, cnt, perm, hbuf);
  egemm2<<<8 * 9 * 12, 256, 0, stream>>>(hbuf, w2T, b2, perm, off, tb, cnt, gate, x1, out);
}